// Round 1
// baseline (256.753 us; speedup 1.0000x reference)
//
#include <hip/hip_runtime.h>
#include <math.h>

#define NN_K 32
#define E_DIM 512
#define CLAMP_V 10000.0f

// ---------------------------------------------------------------------------
// Kernel 1: centroids + pos_encoder (Linear(3,128)+GELU+LayerNorm) + build
// pos_enhanced = concat(x + prompt_signal [:384], pos_enc [128])
// one block (128 threads) per row
// ---------------------------------------------------------------------------
__global__ __launch_bounds__(128) void pos_kernel(
    const float* __restrict__ x, const float* __restrict__ coords9,
    const float* __restrict__ prompt,
    const float* __restrict__ w1, const float* __restrict__ b1,
    const float* __restrict__ ln_g, const float* __restrict__ ln_b,
    float* __restrict__ pos_enh, float* __restrict__ cent, int N)
{
  int n = blockIdx.x;
  int t = threadIdx.x;
  const float* c9 = coords9 + n * 9;
  float c0 = (c9[0] + c9[3] + c9[6]) / 3.0f;
  float c1 = (c9[1] + c9[4] + c9[7]) / 3.0f;
  float c2 = (c9[2] + c9[5] + c9[8]) / 3.0f;
  if (t == 0) { cent[n*3+0] = c0; cent[n*3+1] = c1; cent[n*3+2] = c2; }

  float pre = c0 * w1[t*3+0] + c1 * w1[t*3+1] + c2 * w1[t*3+2] + b1[t];
  // exact GELU: 0.5*x*(1+erf(x/sqrt(2)))
  float g = 0.5f * pre * (1.0f + erff(pre * 0.70710678118654752440f));

  __shared__ float red[4];
  float s = g;
  #pragma unroll
  for (int o = 32; o > 0; o >>= 1) s += __shfl_xor(s, o);
  if ((t & 63) == 0) red[t >> 6] = s;
  __syncthreads();
  float mu = (red[0] + red[1]) * (1.0f / 128.0f);
  float d = g - mu;
  float s2 = d * d;
  #pragma unroll
  for (int o = 32; o > 0; o >>= 1) s2 += __shfl_xor(s2, o);
  if ((t & 63) == 0) red[2 + (t >> 6)] = s2;
  __syncthreads();
  float var = (red[2] + red[3]) * (1.0f / 128.0f);
  float y = d * rsqrtf(var + 1e-5f) * ln_g[t] + ln_b[t];

  pos_enh[(size_t)n * E_DIM + 384 + t] = y;
  #pragma unroll
  for (int j = t; j < 384; j += 128)
    pos_enh[(size_t)n * E_DIM + j] = x[(size_t)n * E_DIM + j] + prompt[j];
}

// ---------------------------------------------------------------------------
// Kernel 2: top-K nearest centroids per row. Tie-break = lowest index
// (matches jax.lax.top_k) via u64 key = (dist_bits<<32)|idx, min-reduce.
// one block (256 threads) per row; keys live in LDS.
// ---------------------------------------------------------------------------
__global__ __launch_bounds__(256) void topk_kernel(
    const float* __restrict__ cent, int* __restrict__ topk, int N)
{
  __shared__ unsigned long long keys[2048];
  __shared__ unsigned long long red[4];
  int n = blockIdx.x;
  int t = threadIdx.x;
  float cx = cent[n*3+0], cy = cent[n*3+1], cz = cent[n*3+2];
  for (int m = t; m < 2048; m += 256) {
    unsigned long long key = ~0ull;
    if (m < N) {
      float dx = cx - cent[m*3+0];
      float dy = cy - cent[m*3+1];
      float dz = cz - cent[m*3+2];
      float dist = sqrtf(dx*dx + dy*dy + dz*dz);
      key = (((unsigned long long)__float_as_uint(dist)) << 32) | (unsigned)m;
    }
    keys[m] = key;
  }
  __syncthreads();
  for (int it = 0; it < NN_K; ++it) {
    unsigned long long lm = ~0ull;
    #pragma unroll
    for (int r = 0; r < 8; ++r) {
      unsigned long long kk = keys[t + r * 256];
      lm = kk < lm ? kk : lm;
    }
    #pragma unroll
    for (int o = 32; o > 0; o >>= 1) {
      unsigned long long other = __shfl_xor(lm, o);
      lm = other < lm ? other : lm;
    }
    if ((t & 63) == 0) red[t >> 6] = lm;
    __syncthreads();
    if (t == 0) {
      unsigned long long b0 = red[0] < red[1] ? red[0] : red[1];
      unsigned long long b1 = red[2] < red[3] ? red[2] : red[3];
      unsigned long long bb = b0 < b1 ? b0 : b1;
      int sel = (int)(bb & 0xffffffffu);
      topk[n * NN_K + it] = sel;
      keys[sel] = ~0ull;   // remove for next iteration
    }
    __syncthreads();
  }
}

// ---------------------------------------------------------------------------
// fp32 tiled GEMM: C[M x 512] = A[M x 512] * W^T (+bias). W is row-major
// (out x in) so both A and W are read along contiguous K. 64x64 tile,
// BK=16, 4x4 acc per thread, 256 threads.
// ---------------------------------------------------------------------------
__device__ __forceinline__ void gemm_tile(
    const float* __restrict__ A, const float* __restrict__ W,
    const float* __restrict__ bias, float* __restrict__ C,
    int M, int K, int ldc, int mtile, int ntile, bool do_clamp)
{
  __shared__ float As[16][68];   // 68-float stride: 272B, 16B-aligned rows
  __shared__ float Bs[16][68];
  int tid = threadIdx.x;
  int tx = tid & 15, ty = tid >> 4;
  int lrow = tid >> 2;           // 0..63
  int lk4  = (tid & 3) << 2;     // 0,4,8,12
  int arow = mtile * 64 + lrow;
  int brow = ntile * 64 + lrow;
  const float* Aptr = A + (size_t)arow * K + lk4;
  const float* Wptr = W + (size_t)brow * K + lk4;
  float acc[4][4] = {{0.f}};

  for (int kk = 0; kk < K; kk += 16) {
    float4 av = make_float4(0.f, 0.f, 0.f, 0.f);
    if (arow < M) av = *(const float4*)(Aptr + kk);
    float4 bv = *(const float4*)(Wptr + kk);
    __syncthreads();
    As[lk4+0][lrow] = av.x; As[lk4+1][lrow] = av.y;
    As[lk4+2][lrow] = av.z; As[lk4+3][lrow] = av.w;
    Bs[lk4+0][lrow] = bv.x; Bs[lk4+1][lrow] = bv.y;
    Bs[lk4+2][lrow] = bv.z; Bs[lk4+3][lrow] = bv.w;
    __syncthreads();
    #pragma unroll
    for (int k2 = 0; k2 < 16; ++k2) {
      float4 a = *(const float4*)&As[k2][ty << 2];
      float4 b = *(const float4*)&Bs[k2][tx << 2];
      acc[0][0] += a.x*b.x; acc[0][1] += a.x*b.y; acc[0][2] += a.x*b.z; acc[0][3] += a.x*b.w;
      acc[1][0] += a.y*b.x; acc[1][1] += a.y*b.y; acc[1][2] += a.y*b.z; acc[1][3] += a.y*b.w;
      acc[2][0] += a.z*b.x; acc[2][1] += a.z*b.y; acc[2][2] += a.z*b.z; acc[2][3] += a.z*b.w;
      acc[3][0] += a.w*b.x; acc[3][1] += a.w*b.y; acc[3][2] += a.w*b.z; acc[3][3] += a.w*b.w;
    }
  }

  int n0 = ntile * 64 + (tx << 2);
  float4 b4 = *(const float4*)&bias[n0];
  float bb[4] = {b4.x, b4.y, b4.z, b4.w};
  #pragma unroll
  for (int i = 0; i < 4; ++i) {
    int row = mtile * 64 + (ty << 2) + i;
    if (row < M) {
      float4 o;
      float* op = &o.x;
      #pragma unroll
      for (int j = 0; j < 4; ++j) {
        float val = acc[i][j] + bb[j];
        if (do_clamp) {
          val = isnan(val) ? 0.0f : val;
          val = fminf(fmaxf(val, -CLAMP_V), CLAMP_V);
        }
        op[j] = val;
      }
      *(float4*)&C[(size_t)row * ldc + n0] = o;
    }
  }
}

__global__ __launch_bounds__(256) void qkv_gemm(
    const float* __restrict__ A,
    const float* __restrict__ wq, const float* __restrict__ wk, const float* __restrict__ wv,
    const float* __restrict__ bq, const float* __restrict__ bk, const float* __restrict__ bv,
    float* __restrict__ q, float* __restrict__ k, float* __restrict__ v, int M)
{
  int sel = blockIdx.y >> 3, ntile = blockIdx.y & 7;
  const float* W = sel == 0 ? wq : (sel == 1 ? wk : wv);
  const float* B = sel == 0 ? bq : (sel == 1 ? bk : bv);
  float* C = sel == 0 ? q : (sel == 1 ? k : v);
  gemm_tile(A, W, B, C, M, E_DIM, E_DIM, blockIdx.x, ntile, false);
}

__global__ __launch_bounds__(256) void out_gemm(
    const float* __restrict__ A, const float* __restrict__ W,
    const float* __restrict__ B, float* __restrict__ C, int M)
{
  gemm_tile(A, W, B, C, M, E_DIM, E_DIM, blockIdx.x, blockIdx.y, true);
}

// ---------------------------------------------------------------------------
// Kernel 4: sparse top-K attention. One block (512 thr = 8 waves) per query;
// wave h handles head h; lane d holds dim d. Coalesced 64-lane k/v row loads,
// butterfly wave-reduce for each of the 32 q.k dots, softmax in registers.
// ---------------------------------------------------------------------------
__global__ __launch_bounds__(512) void attn_kernel(
    const float* __restrict__ q, const float* __restrict__ k, const float* __restrict__ v,
    const int* __restrict__ topk, float* __restrict__ ctx, int N)
{
  int n = blockIdx.x;
  int h = threadIdx.x >> 6;
  int lane = threadIdx.x & 63;
  __shared__ int sidx[NN_K];
  if (threadIdx.x < NN_K) sidx[threadIdx.x] = topk[n * NN_K + threadIdx.x];
  __syncthreads();
  int off = h * 64 + lane;
  float qv = q[(size_t)n * E_DIM + off];
  float s[NN_K];
  #pragma unroll
  for (int j = 0; j < NN_K; ++j) {
    float kv = k[(size_t)sidx[j] * E_DIM + off];
    float p = qv * kv;
    #pragma unroll
    for (int o = 32; o > 0; o >>= 1) p += __shfl_xor(p, o);
    s[j] = p * 0.125f;   // / sqrt(64)
  }
  float mx = s[0];
  #pragma unroll
  for (int j = 1; j < NN_K; ++j) mx = fmaxf(mx, s[j]);
  float l = 0.f;
  #pragma unroll
  for (int j = 0; j < NN_K; ++j) { s[j] = expf(s[j] - mx); l += s[j]; }
  float inv = 1.0f / l;
  float acc = 0.f;
  #pragma unroll
  for (int j = 0; j < NN_K; ++j)
    acc += s[j] * v[(size_t)sidx[j] * E_DIM + off];
  ctx[(size_t)n * E_DIM + off] = acc * inv;
}

// ---------------------------------------------------------------------------
extern "C" void kernel_launch(void* const* d_in, const int* in_sizes, int n_in,
                              void* d_out, int out_size, void* d_ws, size_t ws_size,
                              hipStream_t stream) {
  const float* x       = (const float*)d_in[0];
  const float* coords9 = (const float*)d_in[1];
  const float* prompt  = (const float*)d_in[2];
  const float* pos_w1  = (const float*)d_in[3];
  const float* pos_b1  = (const float*)d_in[4];
  const float* ln_g    = (const float*)d_in[5];
  const float* ln_b    = (const float*)d_in[6];
  const float* wq      = (const float*)d_in[7];
  const float* wk      = (const float*)d_in[8];
  const float* wv      = (const float*)d_in[9];
  const float* bq      = (const float*)d_in[10];
  const float* bk      = (const float*)d_in[11];
  const float* bv      = (const float*)d_in[12];
  const float* wo      = (const float*)d_in[13];
  const float* bo      = (const float*)d_in[14];

  int N = in_sizes[1] / 9;                 // 2000
  size_t NE = (size_t)N * E_DIM;

  float* ws       = (float*)d_ws;
  float* pos_enh  = ws;                    // N*512
  float* qb       = ws + NE;               // N*512
  float* kb       = ws + 2 * NE;           // N*512
  float* vb       = ws + 3 * NE;           // N*512
  float* ctxb     = ws + 4 * NE;           // N*512
  float* cent     = ws + 5 * NE;           // N*3
  int*   topk     = (int*)(ws + 5 * NE + 3 * (size_t)N);  // N*32 ints

  pos_kernel<<<N, 128, 0, stream>>>(x, coords9, prompt, pos_w1, pos_b1,
                                    ln_g, ln_b, pos_enh, cent, N);
  topk_kernel<<<N, 256, 0, stream>>>(cent, topk, N);

  int mt = (N + 63) / 64;                  // 32
  dim3 gq(mt, 24);
  qkv_gemm<<<gq, 256, 0, stream>>>(pos_enh, wq, wk, wv, bq, bk, bv,
                                   qb, kb, vb, N);
  attn_kernel<<<N, 512, 0, stream>>>(qb, kb, vb, topk, ctxb, N);

  dim3 go(mt, 8);
  out_gemm<<<go, 256, 0, stream>>>(ctxb, wo, bo, (float*)d_out, N);
}

// Round 2
// 224.500 us; speedup vs baseline: 1.1437x; 1.1437x over previous
//
#include <hip/hip_runtime.h>
#include <math.h>

#define NN_K 32
#define E_DIM 512
#define CLAMP_V 10000.0f

// ---------------------------------------------------------------------------
// Kernel 1: centroids + pos_encoder (Linear(3,128)+GELU+LayerNorm) + build
// pos_enhanced = concat(x + prompt_signal [:384], pos_enc [128])
// one block (128 threads) per row
// ---------------------------------------------------------------------------
__global__ __launch_bounds__(128) void pos_kernel(
    const float* __restrict__ x, const float* __restrict__ coords9,
    const float* __restrict__ prompt,
    const float* __restrict__ w1, const float* __restrict__ b1,
    const float* __restrict__ ln_g, const float* __restrict__ ln_b,
    float* __restrict__ pos_enh, float* __restrict__ cent, int N)
{
  int n = blockIdx.x;
  int t = threadIdx.x;
  const float* c9 = coords9 + n * 9;
  float c0 = (c9[0] + c9[3] + c9[6]) / 3.0f;
  float c1 = (c9[1] + c9[4] + c9[7]) / 3.0f;
  float c2 = (c9[2] + c9[5] + c9[8]) / 3.0f;
  if (t == 0) { cent[n*3+0] = c0; cent[n*3+1] = c1; cent[n*3+2] = c2; }

  float pre = c0 * w1[t*3+0] + c1 * w1[t*3+1] + c2 * w1[t*3+2] + b1[t];
  // exact GELU: 0.5*x*(1+erf(x/sqrt(2)))
  float g = 0.5f * pre * (1.0f + erff(pre * 0.70710678118654752440f));

  __shared__ float red[4];
  float s = g;
  #pragma unroll
  for (int o = 32; o > 0; o >>= 1) s += __shfl_xor(s, o);
  if ((t & 63) == 0) red[t >> 6] = s;
  __syncthreads();
  float mu = (red[0] + red[1]) * (1.0f / 128.0f);
  float d = g - mu;
  float s2 = d * d;
  #pragma unroll
  for (int o = 32; o > 0; o >>= 1) s2 += __shfl_xor(s2, o);
  if ((t & 63) == 0) red[2 + (t >> 6)] = s2;
  __syncthreads();
  float var = (red[2] + red[3]) * (1.0f / 128.0f);
  float y = d * rsqrtf(var + 1e-5f) * ln_g[t] + ln_b[t];

  pos_enh[(size_t)n * E_DIM + 384 + t] = y;
  #pragma unroll
  for (int j = t; j < 384; j += 128)
    pos_enh[(size_t)n * E_DIM + j] = x[(size_t)n * E_DIM + j] + prompt[j];
}

// ---------------------------------------------------------------------------
// Kernel 2: top-K nearest centroids per row via 4-pass radix select on the
// fp32 distance bits (nonneg fp32 is monotone as u32). Only the SET of K
// indices matters (reference uses them via mask.set(0.0)), so we take all
// dist<T plus the lowest-index elements with dist==T — identical set to
// jax.lax.top_k's stable selection. One block (256 thr) per row; 8 cands/thr.
// ---------------------------------------------------------------------------
__global__ __launch_bounds__(256) void topk_kernel(
    const float* __restrict__ cent, int* __restrict__ topk, int N)
{
  __shared__ unsigned hist[256];
  __shared__ unsigned waveSums[4];
  __shared__ unsigned sel_bin, sel_rem;
  __shared__ unsigned cnt, tcnt;
  __shared__ unsigned tie[2048];

  int n = blockIdx.x;
  int t = threadIdx.x;
  int lane = t & 63, wid = t >> 6;
  float cx = cent[n*3+0], cy = cent[n*3+1], cz = cent[n*3+2];

  unsigned bits[8];
  #pragma unroll
  for (int r = 0; r < 8; ++r) {
    int m = t + (r << 8);
    unsigned b = 0xFFFFFFFFu;           // sentinel > any finite dist
    if (m < N) {
      float dx = cx - cent[m*3+0];
      float dy = cy - cent[m*3+1];
      float dz = cz - cent[m*3+2];
      float dist = sqrtf(dx*dx + dy*dy + dz*dz);   // same expr as R1 (passed)
      b = __float_as_uint(dist);
    }
    bits[r] = b;
  }

  unsigned prefix = 0;
  unsigned K_rem = NN_K;
  #pragma unroll
  for (int p = 0; p < 4; ++p) {
    int shift = 24 - 8 * p;
    unsigned high_mask = (p == 0) ? 0u : (0xFFFFFFFFu << (8 * (4 - p)));
    hist[t] = 0;
    __syncthreads();
    #pragma unroll
    for (int r = 0; r < 8; ++r) {
      if ((bits[r] & high_mask) == prefix)
        atomicAdd(&hist[(bits[r] >> shift) & 255], 1u);
    }
    __syncthreads();
    unsigned h = hist[t];
    unsigned scan = h;                   // inclusive scan over 256 bins
    #pragma unroll
    for (int o = 1; o < 64; o <<= 1) {
      unsigned u = __shfl_up(scan, o);
      if (lane >= o) scan += u;
    }
    if (lane == 63) waveSums[wid] = scan;
    __syncthreads();
    unsigned off = 0;
    for (int w = 0; w < wid; ++w) off += waveSums[w];
    scan += off;
    // unique bin where cumulative count crosses K_rem (requires h>0 there)
    if (scan >= K_rem && (scan - h) < K_rem) {
      sel_bin = (unsigned)t;
      sel_rem = K_rem - (scan - h);
    }
    __syncthreads();
    prefix |= sel_bin << shift;
    K_rem = sel_rem;
    __syncthreads();
  }

  // prefix == exact dist bits T of the K-th smallest; K_rem = #(==T) to take
  unsigned T = prefix;
  if (t == 0) { cnt = 0; tcnt = 0; }
  __syncthreads();
  #pragma unroll
  for (int r = 0; r < 8; ++r) {
    int m = t + (r << 8);
    if (m < N) {
      if (bits[r] < T) {
        unsigned slot = atomicAdd(&cnt, 1u);
        topk[n * NN_K + slot] = m;
      } else if (bits[r] == T) {
        unsigned tp = atomicAdd(&tcnt, 1u);
        tie[tp] = (unsigned)m;
      }
    }
  }
  __syncthreads();
  if (t == 0) {
    unsigned base = cnt;                 // == NN_K - K_rem by construction
    unsigned need = K_rem;               // lowest-index ties win (stable sel)
    for (unsigned it = 0; it < need; ++it) {
      unsigned best = 0xFFFFFFFFu, bj = 0;
      for (unsigned j = 0; j < tcnt; ++j)
        if (tie[j] < best) { best = tie[j]; bj = j; }
      topk[n * NN_K + base + it] = (int)best;
      tie[bj] = 0xFFFFFFFFu;
    }
  }
}

// ---------------------------------------------------------------------------
// fp32 tiled GEMM: C[M x 512] = A[M x 512] * W^T (+bias). W is row-major
// (out x in) so both A and W are read along contiguous K. 64x64 tile,
// BK=16, 4x4 acc per thread, 256 threads.
// ---------------------------------------------------------------------------
__device__ __forceinline__ void gemm_tile(
    const float* __restrict__ A, const float* __restrict__ W,
    const float* __restrict__ bias, float* __restrict__ C,
    int M, int K, int ldc, int mtile, int ntile, bool do_clamp)
{
  __shared__ float As[16][68];   // 68-float stride: 272B, 16B-aligned rows
  __shared__ float Bs[16][68];
  int tid = threadIdx.x;
  int tx = tid & 15, ty = tid >> 4;
  int lrow = tid >> 2;           // 0..63
  int lk4  = (tid & 3) << 2;     // 0,4,8,12
  int arow = mtile * 64 + lrow;
  int brow = ntile * 64 + lrow;
  const float* Aptr = A + (size_t)arow * K + lk4;
  const float* Wptr = W + (size_t)brow * K + lk4;
  float acc[4][4] = {{0.f}};

  for (int kk = 0; kk < K; kk += 16) {
    float4 av = make_float4(0.f, 0.f, 0.f, 0.f);
    if (arow < M) av = *(const float4*)(Aptr + kk);
    float4 bv = *(const float4*)(Wptr + kk);
    __syncthreads();
    As[lk4+0][lrow] = av.x; As[lk4+1][lrow] = av.y;
    As[lk4+2][lrow] = av.z; As[lk4+3][lrow] = av.w;
    Bs[lk4+0][lrow] = bv.x; Bs[lk4+1][lrow] = bv.y;
    Bs[lk4+2][lrow] = bv.z; Bs[lk4+3][lrow] = bv.w;
    __syncthreads();
    #pragma unroll
    for (int k2 = 0; k2 < 16; ++k2) {
      float4 a = *(const float4*)&As[k2][ty << 2];
      float4 b = *(const float4*)&Bs[k2][tx << 2];
      acc[0][0] += a.x*b.x; acc[0][1] += a.x*b.y; acc[0][2] += a.x*b.z; acc[0][3] += a.x*b.w;
      acc[1][0] += a.y*b.x; acc[1][1] += a.y*b.y; acc[1][2] += a.y*b.z; acc[1][3] += a.y*b.w;
      acc[2][0] += a.z*b.x; acc[2][1] += a.z*b.y; acc[2][2] += a.z*b.z; acc[2][3] += a.z*b.w;
      acc[3][0] += a.w*b.x; acc[3][1] += a.w*b.y; acc[3][2] += a.w*b.z; acc[3][3] += a.w*b.w;
    }
  }

  int n0 = ntile * 64 + (tx << 2);
  float4 b4 = *(const float4*)&bias[n0];
  float bb[4] = {b4.x, b4.y, b4.z, b4.w};
  #pragma unroll
  for (int i = 0; i < 4; ++i) {
    int row = mtile * 64 + (ty << 2) + i;
    if (row < M) {
      float4 o;
      float* op = &o.x;
      #pragma unroll
      for (int j = 0; j < 4; ++j) {
        float val = acc[i][j] + bb[j];
        if (do_clamp) {
          val = isnan(val) ? 0.0f : val;
          val = fminf(fmaxf(val, -CLAMP_V), CLAMP_V);
        }
        op[j] = val;
      }
      *(float4*)&C[(size_t)row * ldc + n0] = o;
    }
  }
}

__global__ __launch_bounds__(256) void qkv_gemm(
    const float* __restrict__ A,
    const float* __restrict__ wq, const float* __restrict__ wk, const float* __restrict__ wv,
    const float* __restrict__ bq, const float* __restrict__ bk, const float* __restrict__ bv,
    float* __restrict__ q, float* __restrict__ k, float* __restrict__ v, int M)
{
  int sel = blockIdx.y >> 3, ntile = blockIdx.y & 7;
  const float* W = sel == 0 ? wq : (sel == 1 ? wk : wv);
  const float* B = sel == 0 ? bq : (sel == 1 ? bk : bv);
  float* C = sel == 0 ? q : (sel == 1 ? k : v);
  gemm_tile(A, W, B, C, M, E_DIM, E_DIM, blockIdx.x, ntile, false);
}

__global__ __launch_bounds__(256) void out_gemm(
    const float* __restrict__ A, const float* __restrict__ W,
    const float* __restrict__ B, float* __restrict__ C, int M)
{
  gemm_tile(A, W, B, C, M, E_DIM, E_DIM, blockIdx.x, blockIdx.y, true);
}

// ---------------------------------------------------------------------------
// Kernel 4: sparse top-K attention. One block (512 thr = 8 waves) per query;
// wave h handles head h; lane d holds dim d. Coalesced 64-lane k/v row loads,
// butterfly wave-reduce for each of the 32 q.k dots, softmax in registers.
// ---------------------------------------------------------------------------
__global__ __launch_bounds__(512) void attn_kernel(
    const float* __restrict__ q, const float* __restrict__ k, const float* __restrict__ v,
    const int* __restrict__ topk, float* __restrict__ ctx, int N)
{
  int n = blockIdx.x;
  int h = threadIdx.x >> 6;
  int lane = threadIdx.x & 63;
  __shared__ int sidx[NN_K];
  if (threadIdx.x < NN_K) sidx[threadIdx.x] = topk[n * NN_K + threadIdx.x];
  __syncthreads();
  int off = h * 64 + lane;
  float qv = q[(size_t)n * E_DIM + off];
  float s[NN_K];
  #pragma unroll
  for (int j = 0; j < NN_K; ++j) {
    float kv = k[(size_t)sidx[j] * E_DIM + off];
    float p = qv * kv;
    #pragma unroll
    for (int o = 32; o > 0; o >>= 1) p += __shfl_xor(p, o);
    s[j] = p * 0.125f;   // / sqrt(64)
  }
  float mx = s[0];
  #pragma unroll
  for (int j = 1; j < NN_K; ++j) mx = fmaxf(mx, s[j]);
  float l = 0.f;
  #pragma unroll
  for (int j = 0; j < NN_K; ++j) { s[j] = expf(s[j] - mx); l += s[j]; }
  float inv = 1.0f / l;
  float acc = 0.f;
  #pragma unroll
  for (int j = 0; j < NN_K; ++j)
    acc += s[j] * v[(size_t)sidx[j] * E_DIM + off];
  ctx[(size_t)n * E_DIM + off] = acc * inv;
}

// ---------------------------------------------------------------------------
extern "C" void kernel_launch(void* const* d_in, const int* in_sizes, int n_in,
                              void* d_out, int out_size, void* d_ws, size_t ws_size,
                              hipStream_t stream) {
  const float* x       = (const float*)d_in[0];
  const float* coords9 = (const float*)d_in[1];
  const float* prompt  = (const float*)d_in[2];
  const float* pos_w1  = (const float*)d_in[3];
  const float* pos_b1  = (const float*)d_in[4];
  const float* ln_g    = (const float*)d_in[5];
  const float* ln_b    = (const float*)d_in[6];
  const float* wq      = (const float*)d_in[7];
  const float* wk      = (const float*)d_in[8];
  const float* wv      = (const float*)d_in[9];
  const float* bq      = (const float*)d_in[10];
  const float* bk      = (const float*)d_in[11];
  const float* bv      = (const float*)d_in[12];
  const float* wo      = (const float*)d_in[13];
  const float* bo      = (const float*)d_in[14];

  int N = in_sizes[1] / 9;                 // 2000
  size_t NE = (size_t)N * E_DIM;

  float* ws       = (float*)d_ws;
  float* pos_enh  = ws;                    // N*512
  float* qb       = ws + NE;               // N*512
  float* kb       = ws + 2 * NE;           // N*512
  float* vb       = ws + 3 * NE;           // N*512
  float* ctxb     = ws + 4 * NE;           // N*512
  float* cent     = ws + 5 * NE;           // N*3
  int*   topk     = (int*)(ws + 5 * NE + 3 * (size_t)N);  // N*32 ints

  pos_kernel<<<N, 128, 0, stream>>>(x, coords9, prompt, pos_w1, pos_b1,
                                    ln_g, ln_b, pos_enh, cent, N);
  topk_kernel<<<N, 256, 0, stream>>>(cent, topk, N);

  int mt = (N + 63) / 64;                  // 32
  dim3 gq(mt, 24);
  qkv_gemm<<<gq, 256, 0, stream>>>(pos_enh, wq, wk, wv, bq, bk, bv,
                                   qb, kb, vb, N);
  attn_kernel<<<N, 512, 0, stream>>>(qb, kb, vb, topk, ctxb, N);

  dim3 go(mt, 8);
  out_gemm<<<go, 8 * 32, 0, stream>>>(ctxb, wo, bo, (float*)d_out, N);
}

// Round 3
// 212.362 us; speedup vs baseline: 1.2090x; 1.0572x over previous
//
#include <hip/hip_runtime.h>
#include <math.h>

#define NN_K 32
#define E_DIM 512
#define CLAMP_V 10000.0f

typedef __attribute__((ext_vector_type(8))) short short8;
typedef __attribute__((ext_vector_type(4))) float f32x4;

// bf16 helpers (RTNE), bit-level to avoid type plumbing
__device__ __forceinline__ unsigned short f2bf(float x) {
  unsigned u = __float_as_uint(x);
  unsigned r = u + 0x7fffu + ((u >> 16) & 1u);
  return (unsigned short)(r >> 16);
}
__device__ __forceinline__ float bf2f(unsigned short h) {
  return __uint_as_float(((unsigned)h) << 16);
}
__device__ __forceinline__ void split2(float x, short& h, short& l) {
  unsigned short hh = f2bf(x);
  h = (short)hh;
  l = (short)f2bf(x - bf2f(hh));
}

__device__ __forceinline__ void async16(const void* g, void* l) {
  __builtin_amdgcn_global_load_lds((const __attribute__((address_space(1))) void*)g,
                                   (__attribute__((address_space(3))) void*)l, 16, 0, 0);
}

// ---------------------------------------------------------------------------
// Kernel 0: split the four 512x512 weight matrices into bf16 hi/lo.
// w_hi/w_lo layout: [sel][512][512], sel = 0:wq 1:wk 2:wv 3:wo
// ---------------------------------------------------------------------------
__global__ __launch_bounds__(256) void wsplit_kernel(
    const float* __restrict__ wq, const float* __restrict__ wk,
    const float* __restrict__ wv, const float* __restrict__ wo,
    short* __restrict__ w_hi, short* __restrict__ w_lo)
{
  int v = blockIdx.x * 256 + threadIdx.x;        // 0..262143 float4s
  int m = v >> 16;                               // 65536 float4 per matrix
  int e = v & 0xffff;
  const float* src = m == 0 ? wq : (m == 1 ? wk : (m == 2 ? wv : wo));
  float4 f = ((const float4*)src)[e];
  short4 h, l;
  split2(f.x, h.x, l.x); split2(f.y, h.y, l.y);
  split2(f.z, h.z, l.z); split2(f.w, h.w, l.w);
  ((short4*)w_hi)[v] = h;
  ((short4*)w_lo)[v] = l;
}

// ---------------------------------------------------------------------------
// Kernel 1: centroids + pos_encoder (Linear(3,128)+GELU+LayerNorm) + build
// pos_enhanced = concat(x + prompt [:384], pos_enc [128]) as bf16 hi/lo.
// grid = Mpad rows (pad rows zeroed so GEMM staging reads clean zeros).
// ---------------------------------------------------------------------------
__global__ __launch_bounds__(128) void pos_kernel(
    const float* __restrict__ x, const float* __restrict__ coords9,
    const float* __restrict__ prompt,
    const float* __restrict__ w1, const float* __restrict__ b1,
    const float* __restrict__ ln_g, const float* __restrict__ ln_b,
    short* __restrict__ pos_hi, short* __restrict__ pos_lo,
    float* __restrict__ cent, int N)
{
  int n = blockIdx.x;
  int t = threadIdx.x;
  size_t rb = (size_t)n * E_DIM;
  if (n >= N) {
    #pragma unroll
    for (int j = t; j < E_DIM; j += 128) { pos_hi[rb + j] = 0; pos_lo[rb + j] = 0; }
    return;
  }
  const float* c9 = coords9 + n * 9;
  float c0 = (c9[0] + c9[3] + c9[6]) / 3.0f;
  float c1 = (c9[1] + c9[4] + c9[7]) / 3.0f;
  float c2 = (c9[2] + c9[5] + c9[8]) / 3.0f;
  if (t == 0) { cent[n*3+0] = c0; cent[n*3+1] = c1; cent[n*3+2] = c2; }

  float pre = c0 * w1[t*3+0] + c1 * w1[t*3+1] + c2 * w1[t*3+2] + b1[t];
  float g = 0.5f * pre * (1.0f + erff(pre * 0.70710678118654752440f));

  __shared__ float red[4];
  float s = g;
  #pragma unroll
  for (int o = 32; o > 0; o >>= 1) s += __shfl_xor(s, o);
  if ((t & 63) == 0) red[t >> 6] = s;
  __syncthreads();
  float mu = (red[0] + red[1]) * (1.0f / 128.0f);
  float d = g - mu;
  float s2 = d * d;
  #pragma unroll
  for (int o = 32; o > 0; o >>= 1) s2 += __shfl_xor(s2, o);
  if ((t & 63) == 0) red[2 + (t >> 6)] = s2;
  __syncthreads();
  float var = (red[2] + red[3]) * (1.0f / 128.0f);
  float y = d * rsqrtf(var + 1e-5f) * ln_g[t] + ln_b[t];

  short h, l;
  split2(y, h, l);
  pos_hi[rb + 384 + t] = h;
  pos_lo[rb + 384 + t] = l;
  #pragma unroll
  for (int j = t; j < 384; j += 128) {
    float v = x[rb + j] + prompt[j];
    split2(v, h, l);
    pos_hi[rb + j] = h;
    pos_lo[rb + j] = l;
  }
}

// ---------------------------------------------------------------------------
// Kernel 2: top-K nearest centroids per row via 4-pass radix select (set
// semantics identical to jax.lax.top_k: all dist<T + lowest-index ties).
// ---------------------------------------------------------------------------
__global__ __launch_bounds__(256) void topk_kernel(
    const float* __restrict__ cent, int* __restrict__ topk, int N)
{
  __shared__ unsigned hist[256];
  __shared__ unsigned waveSums[4];
  __shared__ unsigned sel_bin, sel_rem;
  __shared__ unsigned cnt, tcnt;
  __shared__ unsigned tie[2048];

  int n = blockIdx.x;
  int t = threadIdx.x;
  int lane = t & 63, wid = t >> 6;
  float cx = cent[n*3+0], cy = cent[n*3+1], cz = cent[n*3+2];

  unsigned bits[8];
  #pragma unroll
  for (int r = 0; r < 8; ++r) {
    int m = t + (r << 8);
    unsigned b = 0xFFFFFFFFu;
    if (m < N) {
      float dx = cx - cent[m*3+0];
      float dy = cy - cent[m*3+1];
      float dz = cz - cent[m*3+2];
      float dist = sqrtf(dx*dx + dy*dy + dz*dz);
      b = __float_as_uint(dist);
    }
    bits[r] = b;
  }

  unsigned prefix = 0;
  unsigned K_rem = NN_K;
  #pragma unroll
  for (int p = 0; p < 4; ++p) {
    int shift = 24 - 8 * p;
    unsigned high_mask = (p == 0) ? 0u : (0xFFFFFFFFu << (8 * (4 - p)));
    hist[t] = 0;
    __syncthreads();
    #pragma unroll
    for (int r = 0; r < 8; ++r) {
      if ((bits[r] & high_mask) == prefix)
        atomicAdd(&hist[(bits[r] >> shift) & 255], 1u);
    }
    __syncthreads();
    unsigned h = hist[t];
    unsigned scan = h;
    #pragma unroll
    for (int o = 1; o < 64; o <<= 1) {
      unsigned u = __shfl_up(scan, o);
      if (lane >= o) scan += u;
    }
    if (lane == 63) waveSums[wid] = scan;
    __syncthreads();
    unsigned off = 0;
    for (int w = 0; w < wid; ++w) off += waveSums[w];
    scan += off;
    if (scan >= K_rem && (scan - h) < K_rem) {
      sel_bin = (unsigned)t;
      sel_rem = K_rem - (scan - h);
    }
    __syncthreads();
    prefix |= sel_bin << shift;
    K_rem = sel_rem;
    __syncthreads();
  }

  unsigned T = prefix;
  if (t == 0) { cnt = 0; tcnt = 0; }
  __syncthreads();
  #pragma unroll
  for (int r = 0; r < 8; ++r) {
    int m = t + (r << 8);
    if (m < N) {
      if (bits[r] < T) {
        unsigned slot = atomicAdd(&cnt, 1u);
        topk[n * NN_K + slot] = m;
      } else if (bits[r] == T) {
        unsigned tp = atomicAdd(&tcnt, 1u);
        tie[tp] = (unsigned)m;
      }
    }
  }
  __syncthreads();
  if (t == 0) {
    unsigned base = cnt;
    unsigned need = K_rem;
    for (unsigned it = 0; it < need; ++it) {
      unsigned best = 0xFFFFFFFFu, bj = 0;
      for (unsigned j = 0; j < tcnt; ++j)
        if (tie[j] < best) { best = tie[j]; bj = j; }
      topk[n * NN_K + base + it] = (int)best;
      tie[bj] = 0xFFFFFFFFu;
    }
  }
}

// ---------------------------------------------------------------------------
// Split-bf16 MFMA GEMM core (m97 structure): C = A * W^T + bias,
// A = Ah+Al (bf16 hi/lo, [Mpad][512]), W = Wh+Wl ([512][512], row-major n,k).
// 128x128 tile, BK=32, 256 thr = 4 waves each computing a 64x64 quadrant.
// hi*hi + hi*lo + lo*hi via mfma_f32_16x16x32_bf16 (fp32-class accuracy).
// global_load_lds width=16 staging; m97's 2-barrier K-loop.
// ---------------------------------------------------------------------------
__device__ __forceinline__ void gemm_core(
    const short* __restrict__ Ah, const short* __restrict__ Al,
    const short* __restrict__ Wh, const short* __restrict__ Wl,
    const float* __restrict__ bias, float* __restrict__ out,
    int M, int row0, int col0, bool doClamp)
{
  __shared__ short sAh[4096], sAl[4096], sBh[4096], sBl[4096];
  int tid = threadIdx.x;
  int cr = tid >> 2;              // staging chunk row 0..63
  int ck = (tid & 3) << 3;        // k-elem offset 0,8,16,24
  const short* gAh = Ah + (size_t)(row0 + cr) * 512 + ck;
  const short* gAl = Al + (size_t)(row0 + cr) * 512 + ck;
  const short* gBh = Wh + (size_t)(col0 + cr) * 512 + ck;
  const short* gBl = Wl + (size_t)(col0 + cr) * 512 + ck;
  int lo0 = tid * 8, lo1 = (tid + 256) * 8;   // LDS elem offsets (chunk*8)
  const size_t rstep = (size_t)64 * 512;

  int lane = tid & 63, wv_ = tid >> 6;
  int wm = (wv_ & 1) << 6, wn = (wv_ >> 1) << 6;
  int lr = lane & 15, lq = lane >> 4;

  f32x4 acc[4][4];
  #pragma unroll
  for (int i = 0; i < 4; ++i)
    #pragma unroll
    for (int j = 0; j < 4; ++j)
      acc[i][j] = (f32x4){0.f, 0.f, 0.f, 0.f};

  for (int kk = 0; kk < 512; kk += 32) {
    __syncthreads();                       // LDS reusable
    async16(gAh + kk,         &sAh[lo0]);
    async16(gAh + kk + rstep, &sAh[lo1]);
    async16(gAl + kk,         &sAl[lo0]);
    async16(gAl + kk + rstep, &sAl[lo1]);
    async16(gBh + kk,         &sBh[lo0]);
    async16(gBh + kk + rstep, &sBh[lo1]);
    async16(gBl + kk,         &sBl[lo0]);
    async16(gBl + kk + rstep, &sBl[lo1]);
    __syncthreads();                       // drains vmcnt before LDS reads

    short8 ah[4], al[4], bh[4], bl[4];
    #pragma unroll
    for (int i = 0; i < 4; ++i) {
      int ra = (wm + (i << 4) + lr) * 32 + (lq << 3);
      int rb = (wn + (i << 4) + lr) * 32 + (lq << 3);
      ah[i] = *(const short8*)&sAh[ra];
      al[i] = *(const short8*)&sAl[ra];
      bh[i] = *(const short8*)&sBh[rb];
      bl[i] = *(const short8*)&sBl[rb];
    }
    #pragma unroll
    for (int i = 0; i < 4; ++i)
      #pragma unroll
      for (int j = 0; j < 4; ++j) {
        acc[i][j] = __builtin_amdgcn_mfma_f32_16x16x32_bf16(ah[i], bh[j], acc[i][j], 0, 0, 0);
        acc[i][j] = __builtin_amdgcn_mfma_f32_16x16x32_bf16(ah[i], bl[j], acc[i][j], 0, 0, 0);
        acc[i][j] = __builtin_amdgcn_mfma_f32_16x16x32_bf16(al[i], bh[j], acc[i][j], 0, 0, 0);
      }
  }

  // epilogue: C/D layout col=lane&15, row=quad*4+reg  [m89-verified]
  #pragma unroll
  for (int j = 0; j < 4; ++j) {
    float bv_ = bias[col0 + wn + (j << 4) + lr];
    #pragma unroll
    for (int i = 0; i < 4; ++i) {
      #pragma unroll
      for (int r = 0; r < 4; ++r) {
        int grow = row0 + wm + (i << 4) + (lq << 2) + r;
        if (grow < M) {
          float v = acc[i][j][r] + bv_;
          if (doClamp) {
            v = isnan(v) ? 0.0f : v;
            v = fminf(fmaxf(v, -CLAMP_V), CLAMP_V);
          }
          out[(size_t)grow * 512 + col0 + wn + (j << 4) + lr] = v;
        }
      }
    }
  }
}

__global__ __launch_bounds__(256) void qkv_mfma(
    const short* __restrict__ Ah, const short* __restrict__ Al,
    const short* __restrict__ Wh, const short* __restrict__ Wl,
    const float* __restrict__ bq, const float* __restrict__ bk, const float* __restrict__ bv,
    float* __restrict__ qb, float* __restrict__ kb, float* __restrict__ vb, int M)
{
  int sel = blockIdx.y >> 2;           // 0:q 1:k 2:v
  int nblk = blockIdx.y & 3;
  const short* wh = Wh + (size_t)sel * 262144;
  const short* wl = Wl + (size_t)sel * 262144;
  const float* bias = sel == 0 ? bq : (sel == 1 ? bk : bv);
  float* out = sel == 0 ? qb : (sel == 1 ? kb : vb);
  gemm_core(Ah, Al, wh, wl, bias, out, M, blockIdx.x * 128, nblk * 128, false);
}

__global__ __launch_bounds__(256) void out_mfma(
    const short* __restrict__ Ah, const short* __restrict__ Al,
    const short* __restrict__ Wh, const short* __restrict__ Wl,
    const float* __restrict__ bias, float* __restrict__ out, int M)
{
  gemm_core(Ah, Al, Wh + (size_t)3 * 262144, Wl + (size_t)3 * 262144,
            bias, out, M, blockIdx.x * 128, blockIdx.y * 128, true);
}

// ---------------------------------------------------------------------------
// Kernel 4: sparse top-K attention; ctx emitted as bf16 hi/lo for the MFMA
// out-projection. grid = Mpad (pad rows zeroed).
// ---------------------------------------------------------------------------
__global__ __launch_bounds__(512) void attn_kernel(
    const float* __restrict__ q, const float* __restrict__ k, const float* __restrict__ v,
    const int* __restrict__ topk,
    short* __restrict__ ctx_hi, short* __restrict__ ctx_lo, int N)
{
  int n = blockIdx.x;
  size_t rb = (size_t)n * E_DIM;
  if (n >= N) {
    ctx_hi[rb + threadIdx.x] = 0;
    ctx_lo[rb + threadIdx.x] = 0;
    return;
  }
  int h = threadIdx.x >> 6;
  int lane = threadIdx.x & 63;
  __shared__ int sidx[NN_K];
  if (threadIdx.x < NN_K) sidx[threadIdx.x] = topk[n * NN_K + threadIdx.x];
  __syncthreads();
  int off = h * 64 + lane;
  float qv = q[rb + off];
  float s[NN_K];
  #pragma unroll
  for (int j = 0; j < NN_K; ++j) {
    float kv = k[(size_t)sidx[j] * E_DIM + off];
    float p = qv * kv;
    #pragma unroll
    for (int o = 32; o > 0; o >>= 1) p += __shfl_xor(p, o);
    s[j] = p * 0.125f;
  }
  float mx = s[0];
  #pragma unroll
  for (int j = 1; j < NN_K; ++j) mx = fmaxf(mx, s[j]);
  float l = 0.f;
  #pragma unroll
  for (int j = 0; j < NN_K; ++j) { s[j] = expf(s[j] - mx); l += s[j]; }
  float inv = 1.0f / l;
  float acc = 0.f;
  #pragma unroll
  for (int j = 0; j < NN_K; ++j)
    acc += s[j] * v[(size_t)sidx[j] * E_DIM + off];
  float o = acc * inv;
  short hh, ll;
  split2(o, hh, ll);
  ctx_hi[rb + off] = hh;
  ctx_lo[rb + off] = ll;
}

// ---------------------------------------------------------------------------
extern "C" void kernel_launch(void* const* d_in, const int* in_sizes, int n_in,
                              void* d_out, int out_size, void* d_ws, size_t ws_size,
                              hipStream_t stream) {
  const float* x       = (const float*)d_in[0];
  const float* coords9 = (const float*)d_in[1];
  const float* prompt  = (const float*)d_in[2];
  const float* pos_w1  = (const float*)d_in[3];
  const float* pos_b1  = (const float*)d_in[4];
  const float* ln_g    = (const float*)d_in[5];
  const float* ln_b    = (const float*)d_in[6];
  const float* wq      = (const float*)d_in[7];
  const float* wk      = (const float*)d_in[8];
  const float* wv      = (const float*)d_in[9];
  const float* bq      = (const float*)d_in[10];
  const float* bk      = (const float*)d_in[11];
  const float* bv      = (const float*)d_in[12];
  const float* wo      = (const float*)d_in[13];
  const float* bo      = (const float*)d_in[14];

  int N = in_sizes[1] / 9;                       // 2000
  int Mpad = (N + 127) & ~127;                   // 2048
  size_t PE = (size_t)Mpad * E_DIM;              // padded rows * 512

  char* p = (char*)d_ws;
  short* pos_hi = (short*)p; p += PE * 2;        // 2 MB
  short* pos_lo = (short*)p; p += PE * 2;
  short* w_hi   = (short*)p; p += (size_t)4 * 512 * 512 * 2;   // 2 MB
  short* w_lo   = (short*)p; p += (size_t)4 * 512 * 512 * 2;
  float* qb     = (float*)p; p += PE * 4;        // 4 MB
  float* kb     = (float*)p; p += PE * 4;
  float* vb     = (float*)p; p += PE * 4;
  short* ctx_hi = (short*)p; p += PE * 2;
  short* ctx_lo = (short*)p; p += PE * 2;
  float* cent   = (float*)p; p += (size_t)N * 3 * 4;
  int*   topk   = (int*)p;                       // N*32 ints

  wsplit_kernel<<<1024, 256, 0, stream>>>(wq, wk, wv, wo, w_hi, w_lo);
  pos_kernel<<<Mpad, 128, 0, stream>>>(x, coords9, prompt, pos_w1, pos_b1,
                                       ln_g, ln_b, pos_hi, pos_lo, cent, N);
  topk_kernel<<<N, 256, 0, stream>>>(cent, topk, N);

  dim3 gq(Mpad / 128, 12);
  qkv_mfma<<<gq, 256, 0, stream>>>(pos_hi, pos_lo, w_hi, w_lo,
                                   bq, bk, bv, qb, kb, vb, N);
  attn_kernel<<<Mpad, 512, 0, stream>>>(qb, kb, vb, topk, ctx_hi, ctx_lo, N);

  dim3 go(Mpad / 128, 4);
  out_mfma<<<go, 256, 0, stream>>>(ctx_hi, ctx_lo, w_hi, w_lo, bo, (float*)d_out, N);
}

// Round 4
// 188.627 us; speedup vs baseline: 1.3612x; 1.1258x over previous
//
#include <hip/hip_runtime.h>
#include <math.h>

#define NN_K 32
#define E_DIM 512
#define CLAMP_V 10000.0f

typedef __attribute__((ext_vector_type(8))) short short8;
typedef __attribute__((ext_vector_type(4))) float f32x4;

// bf16 RTNE, bit-level
__device__ __forceinline__ unsigned short f2bf(float x) {
  unsigned u = __float_as_uint(x);
  unsigned r = u + 0x7fffu + ((u >> 16) & 1u);
  return (unsigned short)(r >> 16);
}

__device__ __forceinline__ void async16(const void* g, void* l) {
  __builtin_amdgcn_global_load_lds((const __attribute__((address_space(1))) void*)g,
                                   (__attribute__((address_space(3))) void*)l, 16, 0, 0);
}

// ---------------------------------------------------------------------------
// Kernel 0: convert the four 512x512 weight matrices to bf16.
// w_bf layout: [sel][512][512], sel = 0:wq 1:wk 2:wv 3:wo
// ---------------------------------------------------------------------------
__global__ __launch_bounds__(256) void wconv_kernel(
    const float* __restrict__ wq, const float* __restrict__ wk,
    const float* __restrict__ wv, const float* __restrict__ wo,
    short* __restrict__ w_bf)
{
  int v = blockIdx.x * 256 + threadIdx.x;        // 0..262143 float4s
  int m = v >> 16;                               // 65536 float4 per matrix
  int e = v & 0xffff;
  const float* src = m == 0 ? wq : (m == 1 ? wk : (m == 2 ? wv : wo));
  float4 f = ((const float4*)src)[e];
  short4 h;
  h.x = (short)f2bf(f.x); h.y = (short)f2bf(f.y);
  h.z = (short)f2bf(f.z); h.w = (short)f2bf(f.w);
  ((short4*)w_bf)[v] = h;
}

// ---------------------------------------------------------------------------
// Kernel 1: centroids + pos_encoder (Linear(3,128)+GELU+LayerNorm) + build
// pos_enhanced = concat(x + prompt [:384], pos_enc [128]) as bf16.
// grid = Mpad rows (pad rows zeroed so GEMM staging reads clean zeros).
// ---------------------------------------------------------------------------
__global__ __launch_bounds__(128) void pos_kernel(
    const float* __restrict__ x, const float* __restrict__ coords9,
    const float* __restrict__ prompt,
    const float* __restrict__ w1, const float* __restrict__ b1,
    const float* __restrict__ ln_g, const float* __restrict__ ln_b,
    short* __restrict__ pos_bf, float* __restrict__ cent, int N)
{
  int n = blockIdx.x;
  int t = threadIdx.x;
  size_t rb = (size_t)n * E_DIM;
  if (n >= N) {
    #pragma unroll
    for (int j = t; j < E_DIM; j += 128) pos_bf[rb + j] = 0;
    return;
  }
  const float* c9 = coords9 + n * 9;
  float c0 = (c9[0] + c9[3] + c9[6]) / 3.0f;
  float c1 = (c9[1] + c9[4] + c9[7]) / 3.0f;
  float c2 = (c9[2] + c9[5] + c9[8]) / 3.0f;
  if (t == 0) { cent[n*3+0] = c0; cent[n*3+1] = c1; cent[n*3+2] = c2; }

  float pre = c0 * w1[t*3+0] + c1 * w1[t*3+1] + c2 * w1[t*3+2] + b1[t];
  float g = 0.5f * pre * (1.0f + erff(pre * 0.70710678118654752440f));

  __shared__ float red[4];
  float s = g;
  #pragma unroll
  for (int o = 32; o > 0; o >>= 1) s += __shfl_xor(s, o);
  if ((t & 63) == 0) red[t >> 6] = s;
  __syncthreads();
  float mu = (red[0] + red[1]) * (1.0f / 128.0f);
  float d = g - mu;
  float s2 = d * d;
  #pragma unroll
  for (int o = 32; o > 0; o >>= 1) s2 += __shfl_xor(s2, o);
  if ((t & 63) == 0) red[2 + (t >> 6)] = s2;
  __syncthreads();
  float var = (red[2] + red[3]) * (1.0f / 128.0f);
  float y = d * rsqrtf(var + 1e-5f) * ln_g[t] + ln_b[t];

  pos_bf[rb + 384 + t] = (short)f2bf(y);
  #pragma unroll
  for (int j = t; j < 384; j += 128)
    pos_bf[rb + j] = (short)f2bf(x[rb + j] + prompt[j]);
}

// ---------------------------------------------------------------------------
// Kernel 2: top-K nearest centroids per row via 4-pass radix select (set
// semantics identical to jax.lax.top_k: all dist<T + lowest-index ties).
// ---------------------------------------------------------------------------
__global__ __launch_bounds__(256) void topk_kernel(
    const float* __restrict__ cent, int* __restrict__ topk, int N)
{
  __shared__ unsigned hist[256];
  __shared__ unsigned waveSums[4];
  __shared__ unsigned sel_bin, sel_rem;
  __shared__ unsigned cnt, tcnt;
  __shared__ unsigned tie[2048];

  int n = blockIdx.x;
  int t = threadIdx.x;
  int lane = t & 63, wid = t >> 6;
  float cx = cent[n*3+0], cy = cent[n*3+1], cz = cent[n*3+2];

  unsigned bits[8];
  #pragma unroll
  for (int r = 0; r < 8; ++r) {
    int m = t + (r << 8);
    unsigned b = 0xFFFFFFFFu;
    if (m < N) {
      float dx = cx - cent[m*3+0];
      float dy = cy - cent[m*3+1];
      float dz = cz - cent[m*3+2];
      float dist = sqrtf(dx*dx + dy*dy + dz*dz);
      b = __float_as_uint(dist);
    }
    bits[r] = b;
  }

  unsigned prefix = 0;
  unsigned K_rem = NN_K;
  #pragma unroll
  for (int p = 0; p < 4; ++p) {
    int shift = 24 - 8 * p;
    unsigned high_mask = (p == 0) ? 0u : (0xFFFFFFFFu << (8 * (4 - p)));
    hist[t] = 0;
    __syncthreads();
    #pragma unroll
    for (int r = 0; r < 8; ++r) {
      if ((bits[r] & high_mask) == prefix)
        atomicAdd(&hist[(bits[r] >> shift) & 255], 1u);
    }
    __syncthreads();
    unsigned h = hist[t];
    unsigned scan = h;
    #pragma unroll
    for (int o = 1; o < 64; o <<= 1) {
      unsigned u = __shfl_up(scan, o);
      if (lane >= o) scan += u;
    }
    if (lane == 63) waveSums[wid] = scan;
    __syncthreads();
    unsigned off = 0;
    for (int w = 0; w < wid; ++w) off += waveSums[w];
    scan += off;
    if (scan >= K_rem && (scan - h) < K_rem) {
      sel_bin = (unsigned)t;
      sel_rem = K_rem - (scan - h);
    }
    __syncthreads();
    prefix |= sel_bin << shift;
    K_rem = sel_rem;
    __syncthreads();
  }

  unsigned T = prefix;
  if (t == 0) { cnt = 0; tcnt = 0; }
  __syncthreads();
  #pragma unroll
  for (int r = 0; r < 8; ++r) {
    int m = t + (r << 8);
    if (m < N) {
      if (bits[r] < T) {
        unsigned slot = atomicAdd(&cnt, 1u);
        topk[n * NN_K + slot] = m;
      } else if (bits[r] == T) {
        unsigned tp = atomicAdd(&tcnt, 1u);
        tie[tp] = (unsigned)m;
      }
    }
  }
  __syncthreads();
  if (t == 0) {
    unsigned base = cnt;
    unsigned need = K_rem;
    for (unsigned it = 0; it < need; ++it) {
      unsigned best = 0xFFFFFFFFu, bj = 0;
      for (unsigned j = 0; j < tcnt; ++j)
        if (tie[j] < best) { best = tie[j]; bj = j; }
      topk[n * NN_K + base + it] = (int)best;
      tie[bj] = 0xFFFFFFFFu;
    }
  }
}

// ---------------------------------------------------------------------------
// bf16 MFMA GEMM, double-buffered LDS pipeline: C = A * W^T + bias.
// A bf16 [Mpad][512]; W bf16 [512][512] (row-major n,k). 128x128 tile,
// BK=32, 256 thr = 4 waves each computing a 64x64 quadrant.
// Raw s_waitcnt vmcnt(4)+s_barrier keeps the next tile's global_load_lds in
// flight across the barrier (unlike __syncthreads' vmcnt(0) drain) — this is
// the fine-vmcnt pipeline; at 1 block/CU there are no other waves to hide
// the load latency, so the prefetch is structural, not optional.
// ---------------------------------------------------------------------------
__device__ __forceinline__ void gemm_core(
    const short* __restrict__ A, const short* __restrict__ W,
    const float* __restrict__ bias, float* __restrict__ out,
    int M, int row0, int col0, bool doClamp)
{
  __shared__ short sA[2][4096], sB[2][4096];   // 32 KB total
  int tid = threadIdx.x;
  int cr = tid >> 2;              // staging row 0..63 (chunk1: +64)
  int ck = (tid & 3) << 3;        // k offset 0,8,16,24
  const short* gA = A + (size_t)(row0 + cr) * 512 + ck;
  const short* gB = W + (size_t)(col0 + cr) * 512 + ck;
  int lo0 = tid * 8, lo1 = (tid + 256) * 8;   // LDS short offsets
  const size_t rstep = (size_t)64 * 512;

  int lane = tid & 63, wv_ = tid >> 6;
  int wm = (wv_ & 1) << 6, wn = (wv_ >> 1) << 6;
  int lr = lane & 15, lq = lane >> 4;

#define STAGE(t, b) do { \
    async16(gA + (t) * 32,         &sA[b][lo0]); \
    async16(gA + (t) * 32 + rstep, &sA[b][lo1]); \
    async16(gB + (t) * 32,         &sB[b][lo0]); \
    async16(gB + (t) * 32 + rstep, &sB[b][lo1]); } while (0)

  STAGE(0, 0);
  STAGE(1, 1);

  f32x4 acc[4][4];
  #pragma unroll
  for (int i = 0; i < 4; ++i)
    #pragma unroll
    for (int j = 0; j < 4; ++j)
      acc[i][j] = (f32x4){0.f, 0.f, 0.f, 0.f};

  #pragma unroll
  for (int it = 0; it < 16; ++it) {
    int cur = it & 1;
    // barrier1: own tile-`it` loads landed (4 newest may stay in flight)
    if (it == 15) asm volatile("s_waitcnt vmcnt(0)\ns_barrier" ::: "memory");
    else          asm volatile("s_waitcnt vmcnt(4)\ns_barrier" ::: "memory");

    short8 af[4], bf[4];
    #pragma unroll
    for (int i = 0; i < 4; ++i) {
      af[i] = *(const short8*)&sA[cur][(wm + (i << 4) + lr) * 32 + (lq << 3)];
      bf[i] = *(const short8*)&sB[cur][(wn + (i << 4) + lr) * 32 + (lq << 3)];
    }
    #pragma unroll
    for (int i = 0; i < 4; ++i)
      #pragma unroll
      for (int j = 0; j < 4; ++j)
        acc[i][j] = __builtin_amdgcn_mfma_f32_16x16x32_bf16(af[i], bf[j], acc[i][j], 0, 0, 0);

    // barrier2: all waves done reading buf[cur] -> safe to restage into it
    asm volatile("s_waitcnt lgkmcnt(0)\ns_barrier" ::: "memory");
    if (it + 2 < 16) STAGE(it + 2, cur);
  }
#undef STAGE

  // epilogue: C/D layout col=lane&15, row=quad*4+reg  [m89-verified]
  #pragma unroll
  for (int j = 0; j < 4; ++j) {
    float bv_ = bias[col0 + wn + (j << 4) + lr];
    #pragma unroll
    for (int i = 0; i < 4; ++i) {
      #pragma unroll
      for (int r = 0; r < 4; ++r) {
        int grow = row0 + wm + (i << 4) + (lq << 2) + r;
        if (grow < M) {
          float v = acc[i][j][r] + bv_;
          if (doClamp) {
            v = isnan(v) ? 0.0f : v;
            v = fminf(fmaxf(v, -CLAMP_V), CLAMP_V);
          }
          out[(size_t)grow * 512 + col0 + wn + (j << 4) + lr] = v;
        }
      }
    }
  }
}

__global__ __launch_bounds__(256) void qkv_mfma(
    const short* __restrict__ A, const short* __restrict__ Wb,
    const float* __restrict__ bq, const float* __restrict__ bk, const float* __restrict__ bv,
    float* __restrict__ qb, float* __restrict__ kb, float* __restrict__ vb, int M)
{
  int sel = blockIdx.y >> 2;           // 0:q 1:k 2:v
  int nblk = blockIdx.y & 3;
  const short* w = Wb + (size_t)sel * 262144;
  const float* bias = sel == 0 ? bq : (sel == 1 ? bk : bv);
  float* out = sel == 0 ? qb : (sel == 1 ? kb : vb);
  gemm_core(A, w, bias, out, M, blockIdx.x * 128, nblk * 128, false);
}

__global__ __launch_bounds__(256) void out_mfma(
    const short* __restrict__ A, const short* __restrict__ Wb,
    const float* __restrict__ bias, float* __restrict__ out, int M)
{
  gemm_core(A, Wb + (size_t)3 * 262144, bias, out, M,
            blockIdx.x * 128, blockIdx.y * 128, true);
}

// ---------------------------------------------------------------------------
// Kernel 4: sparse top-K attention; ctx emitted as bf16 for the MFMA
// out-projection. grid = Mpad (pad rows zeroed).
// ---------------------------------------------------------------------------
__global__ __launch_bounds__(512) void attn_kernel(
    const float* __restrict__ q, const float* __restrict__ k, const float* __restrict__ v,
    const int* __restrict__ topk, short* __restrict__ ctx_bf, int N)
{
  int n = blockIdx.x;
  size_t rb = (size_t)n * E_DIM;
  if (n >= N) {
    ctx_bf[rb + threadIdx.x] = 0;
    return;
  }
  int h = threadIdx.x >> 6;
  int lane = threadIdx.x & 63;
  __shared__ int sidx[NN_K];
  if (threadIdx.x < NN_K) sidx[threadIdx.x] = topk[n * NN_K + threadIdx.x];
  __syncthreads();
  int off = h * 64 + lane;
  float qv = q[rb + off];
  float s[NN_K];
  #pragma unroll
  for (int j = 0; j < NN_K; ++j) {
    float kv = k[(size_t)sidx[j] * E_DIM + off];
    float p = qv * kv;
    #pragma unroll
    for (int o = 32; o > 0; o >>= 1) p += __shfl_xor(p, o);
    s[j] = p * 0.125f;
  }
  float mx = s[0];
  #pragma unroll
  for (int j = 1; j < NN_K; ++j) mx = fmaxf(mx, s[j]);
  float l = 0.f;
  #pragma unroll
  for (int j = 0; j < NN_K; ++j) { s[j] = expf(s[j] - mx); l += s[j]; }
  float inv = 1.0f / l;
  float acc = 0.f;
  #pragma unroll
  for (int j = 0; j < NN_K; ++j)
    acc += s[j] * v[(size_t)sidx[j] * E_DIM + off];
  ctx_bf[rb + off] = (short)f2bf(acc * inv);
}

// ---------------------------------------------------------------------------
extern "C" void kernel_launch(void* const* d_in, const int* in_sizes, int n_in,
                              void* d_out, int out_size, void* d_ws, size_t ws_size,
                              hipStream_t stream) {
  const float* x       = (const float*)d_in[0];
  const float* coords9 = (const float*)d_in[1];
  const float* prompt  = (const float*)d_in[2];
  const float* pos_w1  = (const float*)d_in[3];
  const float* pos_b1  = (const float*)d_in[4];
  const float* ln_g    = (const float*)d_in[5];
  const float* ln_b    = (const float*)d_in[6];
  const float* wq      = (const float*)d_in[7];
  const float* wk      = (const float*)d_in[8];
  const float* wv      = (const float*)d_in[9];
  const float* bq      = (const float*)d_in[10];
  const float* bk      = (const float*)d_in[11];
  const float* bv      = (const float*)d_in[12];
  const float* wo      = (const float*)d_in[13];
  const float* bo      = (const float*)d_in[14];

  int N = in_sizes[1] / 9;                       // 2000
  int Mpad = (N + 127) & ~127;                   // 2048
  size_t PE = (size_t)Mpad * E_DIM;

  char* p = (char*)d_ws;
  short* pos_bf = (short*)p; p += PE * 2;                      // 2 MB
  short* w_bf   = (short*)p; p += (size_t)4 * 512 * 512 * 2;   // 2 MB
  float* qb     = (float*)p; p += PE * 4;                      // 4 MB
  float* kb     = (float*)p; p += PE * 4;
  float* vb     = (float*)p; p += PE * 4;
  short* ctx_bf = (short*)p; p += PE * 2;
  float* cent   = (float*)p; p += (size_t)N * 3 * 4;
  int*   topk   = (int*)p;                                     // N*32 ints

  wconv_kernel<<<1024, 256, 0, stream>>>(wq, wk, wv, wo, w_bf);
  pos_kernel<<<Mpad, 128, 0, stream>>>(x, coords9, prompt, pos_w1, pos_b1,
                                       ln_g, ln_b, pos_bf, cent, N);
  topk_kernel<<<N, 256, 0, stream>>>(cent, topk, N);

  dim3 gq(Mpad / 128, 12);
  qkv_mfma<<<gq, 256, 0, stream>>>(pos_bf, w_bf, bq, bk, bv, qb, kb, vb, N);
  attn_kernel<<<Mpad, 512, 0, stream>>>(qb, kb, vb, topk, ctx_bf, N);

  dim3 go(Mpad / 128, 4);
  out_mfma<<<go, 256, 0, stream>>>(ctx_bf, w_bf, bo, (float*)d_out, N);
}

// Round 5
// 167.994 us; speedup vs baseline: 1.5283x; 1.1228x over previous
//
#include <hip/hip_runtime.h>
#include <math.h>

#define NN_K 32
#define E_DIM 512
#define CLAMP_V 10000.0f

typedef __attribute__((ext_vector_type(8))) short short8;
typedef __attribute__((ext_vector_type(4))) float f32x4;

// bf16 RTNE, bit-level
__device__ __forceinline__ unsigned short f2bf(float x) {
  unsigned u = __float_as_uint(x);
  unsigned r = u + 0x7fffu + ((u >> 16) & 1u);
  return (unsigned short)(r >> 16);
}
__device__ __forceinline__ float bf2f_bits(short h) {
  return __uint_as_float(((unsigned)(unsigned short)h) << 16);
}

__device__ __forceinline__ void async16(const void* g, void* l) {
  __builtin_amdgcn_global_load_lds((const __attribute__((address_space(1))) void*)g,
                                   (__attribute__((address_space(3))) void*)l, 16, 0, 0);
}

// ---------------------------------------------------------------------------
// Kernel 0: convert the four 512x512 weight matrices to bf16.
// ---------------------------------------------------------------------------
__global__ __launch_bounds__(256) void wconv_kernel(
    const float* __restrict__ wq, const float* __restrict__ wk,
    const float* __restrict__ wv, const float* __restrict__ wo,
    short* __restrict__ w_bf)
{
  int v = blockIdx.x * 256 + threadIdx.x;
  int m = v >> 16;
  int e = v & 0xffff;
  const float* src = m == 0 ? wq : (m == 1 ? wk : (m == 2 ? wv : wo));
  float4 f = ((const float4*)src)[e];
  short4 h;
  h.x = (short)f2bf(f.x); h.y = (short)f2bf(f.y);
  h.z = (short)f2bf(f.z); h.w = (short)f2bf(f.w);
  ((short4*)w_bf)[v] = h;
}

// ---------------------------------------------------------------------------
// Kernel 1: centroids + pos_encoder + pos_enhanced (bf16). Pad rows zeroed.
// ---------------------------------------------------------------------------
__global__ __launch_bounds__(128) void pos_kernel(
    const float* __restrict__ x, const float* __restrict__ coords9,
    const float* __restrict__ prompt,
    const float* __restrict__ w1, const float* __restrict__ b1,
    const float* __restrict__ ln_g, const float* __restrict__ ln_b,
    short* __restrict__ pos_bf, float* __restrict__ cent, int N)
{
  int n = blockIdx.x;
  int t = threadIdx.x;
  size_t rb = (size_t)n * E_DIM;
  if (n >= N) {
    #pragma unroll
    for (int j = t; j < E_DIM; j += 128) pos_bf[rb + j] = 0;
    return;
  }
  const float* c9 = coords9 + n * 9;
  float c0 = (c9[0] + c9[3] + c9[6]) / 3.0f;
  float c1 = (c9[1] + c9[4] + c9[7]) / 3.0f;
  float c2 = (c9[2] + c9[5] + c9[8]) / 3.0f;
  if (t == 0) { cent[n*3+0] = c0; cent[n*3+1] = c1; cent[n*3+2] = c2; }

  float pre = c0 * w1[t*3+0] + c1 * w1[t*3+1] + c2 * w1[t*3+2] + b1[t];
  float g = 0.5f * pre * (1.0f + erff(pre * 0.70710678118654752440f));

  __shared__ float red[4];
  float s = g;
  #pragma unroll
  for (int o = 32; o > 0; o >>= 1) s += __shfl_xor(s, o);
  if ((t & 63) == 0) red[t >> 6] = s;
  __syncthreads();
  float mu = (red[0] + red[1]) * (1.0f / 128.0f);
  float d = g - mu;
  float s2 = d * d;
  #pragma unroll
  for (int o = 32; o > 0; o >>= 1) s2 += __shfl_xor(s2, o);
  if ((t & 63) == 0) red[2 + (t >> 6)] = s2;
  __syncthreads();
  float var = (red[2] + red[3]) * (1.0f / 128.0f);
  float y = d * rsqrtf(var + 1e-5f) * ln_g[t] + ln_b[t];

  pos_bf[rb + 384 + t] = (short)f2bf(y);
  #pragma unroll
  for (int j = t; j < 384; j += 128)
    pos_bf[rb + j] = (short)f2bf(x[rb + j] + prompt[j]);
}

// ---------------------------------------------------------------------------
// Kernel 2: top-K nearest centroids, 4-pass radix select (set semantics
// identical to jax.lax.top_k: all dist<T + lowest-index ties).
// ---------------------------------------------------------------------------
__global__ __launch_bounds__(256) void topk_kernel(
    const float* __restrict__ cent, int* __restrict__ topk, int N)
{
  __shared__ unsigned hist[256];
  __shared__ unsigned waveSums[4];
  __shared__ unsigned sel_bin, sel_rem;
  __shared__ unsigned cnt, tcnt;
  __shared__ unsigned tie[2048];

  int n = blockIdx.x;
  int t = threadIdx.x;
  int lane = t & 63, wid = t >> 6;
  float cx = cent[n*3+0], cy = cent[n*3+1], cz = cent[n*3+2];

  unsigned bits[8];
  #pragma unroll
  for (int r = 0; r < 8; ++r) {
    int m = t + (r << 8);
    unsigned b = 0xFFFFFFFFu;
    if (m < N) {
      float dx = cx - cent[m*3+0];
      float dy = cy - cent[m*3+1];
      float dz = cz - cent[m*3+2];
      float dist = sqrtf(dx*dx + dy*dy + dz*dz);
      b = __float_as_uint(dist);
    }
    bits[r] = b;
  }

  unsigned prefix = 0;
  unsigned K_rem = NN_K;
  #pragma unroll
  for (int p = 0; p < 4; ++p) {
    int shift = 24 - 8 * p;
    unsigned high_mask = (p == 0) ? 0u : (0xFFFFFFFFu << (8 * (4 - p)));
    hist[t] = 0;
    __syncthreads();
    #pragma unroll
    for (int r = 0; r < 8; ++r) {
      if ((bits[r] & high_mask) == prefix)
        atomicAdd(&hist[(bits[r] >> shift) & 255], 1u);
    }
    __syncthreads();
    unsigned h = hist[t];
    unsigned scan = h;
    #pragma unroll
    for (int o = 1; o < 64; o <<= 1) {
      unsigned u = __shfl_up(scan, o);
      if (lane >= o) scan += u;
    }
    if (lane == 63) waveSums[wid] = scan;
    __syncthreads();
    unsigned off = 0;
    for (int w = 0; w < wid; ++w) off += waveSums[w];
    scan += off;
    if (scan >= K_rem && (scan - h) < K_rem) {
      sel_bin = (unsigned)t;
      sel_rem = K_rem - (scan - h);
    }
    __syncthreads();
    prefix |= sel_bin << shift;
    K_rem = sel_rem;
    __syncthreads();
  }

  unsigned T = prefix;
  if (t == 0) { cnt = 0; tcnt = 0; }
  __syncthreads();
  #pragma unroll
  for (int r = 0; r < 8; ++r) {
    int m = t + (r << 8);
    if (m < N) {
      if (bits[r] < T) {
        unsigned slot = atomicAdd(&cnt, 1u);
        topk[n * NN_K + slot] = m;
      } else if (bits[r] == T) {
        unsigned tp = atomicAdd(&tcnt, 1u);
        tie[tp] = (unsigned)m;
      }
    }
  }
  __syncthreads();
  if (t == 0) {
    unsigned base = cnt;
    unsigned need = K_rem;
    for (unsigned it = 0; it < need; ++it) {
      unsigned best = 0xFFFFFFFFu, bj = 0;
      for (unsigned j = 0; j < tcnt; ++j)
        if (tie[j] < best) { best = tie[j]; bj = j; }
      topk[n * NN_K + base + it] = (int)best;
      tie[bj] = 0xFFFFFFFFu;
    }
  }
}

// ---------------------------------------------------------------------------
// bf16 MFMA GEMM, double-buffered with raw vmcnt(4)+s_barrier pipeline.
// Output either fp32 (outf, ld=512) or bf16 (outb, ld=out_ld, col offset).
// ---------------------------------------------------------------------------
__device__ __forceinline__ void gemm_core(
    const short* __restrict__ A, const short* __restrict__ W,
    const float* __restrict__ bias,
    float* __restrict__ outf, short* __restrict__ outb,
    int out_ld, int out_c0,
    int M, int row0, int col0, bool doClamp)
{
  __shared__ short sA[2][4096], sB[2][4096];
  int tid = threadIdx.x;
  int cr = tid >> 2;
  int ck = (tid & 3) << 3;
  const short* gA = A + (size_t)(row0 + cr) * 512 + ck;
  const short* gB = W + (size_t)(col0 + cr) * 512 + ck;
  int lo0 = tid * 8, lo1 = (tid + 256) * 8;
  const size_t rstep = (size_t)64 * 512;

  int lane = tid & 63, wv_ = tid >> 6;
  int wm = (wv_ & 1) << 6, wn = (wv_ >> 1) << 6;
  int lr = lane & 15, lq = lane >> 4;

#define STAGE(t, b) do { \
    async16(gA + (t) * 32,         &sA[b][lo0]); \
    async16(gA + (t) * 32 + rstep, &sA[b][lo1]); \
    async16(gB + (t) * 32,         &sB[b][lo0]); \
    async16(gB + (t) * 32 + rstep, &sB[b][lo1]); } while (0)

  STAGE(0, 0);
  STAGE(1, 1);

  f32x4 acc[4][4];
  #pragma unroll
  for (int i = 0; i < 4; ++i)
    #pragma unroll
    for (int j = 0; j < 4; ++j)
      acc[i][j] = (f32x4){0.f, 0.f, 0.f, 0.f};

  #pragma unroll
  for (int it = 0; it < 16; ++it) {
    int cur = it & 1;
    if (it == 15) asm volatile("s_waitcnt vmcnt(0)\ns_barrier" ::: "memory");
    else          asm volatile("s_waitcnt vmcnt(4)\ns_barrier" ::: "memory");

    short8 af[4], bf[4];
    #pragma unroll
    for (int i = 0; i < 4; ++i) {
      af[i] = *(const short8*)&sA[cur][(wm + (i << 4) + lr) * 32 + (lq << 3)];
      bf[i] = *(const short8*)&sB[cur][(wn + (i << 4) + lr) * 32 + (lq << 3)];
    }
    #pragma unroll
    for (int i = 0; i < 4; ++i)
      #pragma unroll
      for (int j = 0; j < 4; ++j)
        acc[i][j] = __builtin_amdgcn_mfma_f32_16x16x32_bf16(af[i], bf[j], acc[i][j], 0, 0, 0);

    asm volatile("s_waitcnt lgkmcnt(0)\ns_barrier" ::: "memory");
    if (it + 2 < 16) STAGE(it + 2, cur);
  }
#undef STAGE

  #pragma unroll
  for (int j = 0; j < 4; ++j) {
    int gcol = col0 + wn + (j << 4) + lr;
    float bv_ = bias[gcol];
    #pragma unroll
    for (int i = 0; i < 4; ++i) {
      #pragma unroll
      for (int r = 0; r < 4; ++r) {
        int grow = row0 + wm + (i << 4) + (lq << 2) + r;
        if (grow < M) {
          float v = acc[i][j][r] + bv_;
          if (doClamp) {
            v = isnan(v) ? 0.0f : v;
            v = fminf(fmaxf(v, -CLAMP_V), CLAMP_V);
          }
          if (outf) outf[(size_t)grow * 512 + gcol] = v;
          else      outb[(size_t)grow * out_ld + out_c0 + gcol] = (short)f2bf(v);
        }
      }
    }
  }
}

__global__ __launch_bounds__(256) void qkv_mfma(
    const short* __restrict__ A, const short* __restrict__ Wb,
    const float* __restrict__ bq, const float* __restrict__ bk, const float* __restrict__ bv,
    float* __restrict__ qb, short* __restrict__ kv, int M)
{
  int sel = blockIdx.y >> 2;
  int nblk = blockIdx.y & 3;
  int r0 = blockIdx.x * 128, c0 = nblk * 128;
  if (sel == 0)
    gemm_core(A, Wb, bq, qb, nullptr, 512, 0, M, r0, c0, false);
  else if (sel == 1)
    gemm_core(A, Wb + 262144, bk, nullptr, kv, 1024, 0, M, r0, c0, false);
  else
    gemm_core(A, Wb + 2 * 262144, bv, nullptr, kv, 1024, 512, M, r0, c0, false);
}

__global__ __launch_bounds__(256) void out_mfma(
    const short* __restrict__ A, const short* __restrict__ Wb,
    const float* __restrict__ bias, float* __restrict__ out, int M)
{
  gemm_core(A, Wb + (size_t)3 * 262144, bias, out, nullptr, 512, 0, M,
            blockIdx.x * 128, blockIdx.y * 128, true);
}

// ---------------------------------------------------------------------------
// Kernel 4: sparse top-K attention, lane-per-key scores.
// Block = 1 query (512 thr, wave = head). k rows staged in LDS with XOR-4
// swizzle (b64-contiguous writes, <=2-way-bank column reads). Scores: lane
// (key,half) serial 32-dim dot + 1 merge shuffle (vs 6/key butterfly).
// ctx: lane = dim, coalesced bf16 v gathers, p via LDS b128 broadcast.
// ---------------------------------------------------------------------------
__global__ __launch_bounds__(512) void attn_kernel(
    const float* __restrict__ qb, const short* __restrict__ kv,
    const int* __restrict__ topk, short* __restrict__ ctx_bf, int N)
{
  __shared__ short klds[32 * 512];     // 32 KB, swizzled rows
  __shared__ int sidx[NN_K];
  __shared__ float plds[8 * 32];

  int n = blockIdx.x;
  int tid = threadIdx.x;
  size_t rb = (size_t)n * E_DIM;
  if (n >= N) { ctx_bf[rb + tid] = 0; return; }

  if (tid < NN_K) sidx[tid] = topk[n * NN_K + tid];
  __syncthreads();

  int h = tid >> 6, lane = tid & 63;
  int jk = lane & 31, half = lane >> 5;
  int dbase = h * 64 + half * 32;

  // ---- preload q head-slice to regs (broadcast within 32-group) ----
  float qv[32];
  {
    const float4* qs = (const float4*)(qb + rb + dbase);
    #pragma unroll
    for (int b = 0; b < 8; ++b) {
      float4 f = qs[b];
      qv[b*4+0] = f.x; qv[b*4+1] = f.y; qv[b*4+2] = f.z; qv[b*4+3] = f.w;
    }
  }

  // ---- stage k rows: thread t -> row j=t>>4, 32 halfs at d0=(t&15)*32 ----
  {
    int j = tid >> 4, a = tid & 15;
    const short8* src = (const short8*)(kv + (size_t)sidx[j] * 1024 + a * 32);
    int sw = 4 * (j & 15);
    short* row = &klds[j * 512];
    #pragma unroll
    for (int b = 0; b < 4; ++b) {
      short8 val = src[b];
      int d0 = a * 32 + b * 8;
      *(short4*)&row[(d0    ) ^ sw] = *(const short4*)&val;
      *(short4*)&row[(d0 + 4) ^ sw] = *((const short4*)&val + 1);
    }
  }
  __syncthreads();

  // ---- scores: lane (jk, half) serial dot over its 32 dims ----
  float s = 0.f;
  {
    int sw = 4 * (jk & 15);
    const short* krow = &klds[jk * 512];
    #pragma unroll
    for (int i = 0; i < 32; ++i) {
      int d = (dbase + i) ^ sw;
      s += qv[i] * bf2f_bits(krow[d]);
    }
  }
  s += __shfl_xor(s, 32);              // merge halves: full 64-dim dot
  s *= 0.125f;                          // / sqrt(64)

  // ---- softmax over 32 keys (within 32-lane group) ----
  float mx = s;
  #pragma unroll
  for (int o = 16; o > 0; o >>= 1) mx = fmaxf(mx, __shfl_xor(mx, o));
  float p = expf(s - mx);
  float l = p;
  #pragma unroll
  for (int o = 16; o > 0; o >>= 1) l += __shfl_xor(l, o);
  p *= (1.0f / l);
  if (half == 0) plds[h * 32 + jk] = p;
  __syncthreads();

  // ---- preload p via lane-uniform b128 broadcasts ----
  float pv[32];
  #pragma unroll
  for (int b = 0; b < 8; ++b) {
    float4 f = *(const float4*)&plds[h * 32 + b * 4];
    pv[b*4+0] = f.x; pv[b*4+1] = f.y; pv[b*4+2] = f.z; pv[b*4+3] = f.w;
  }

  // ---- ctx: lane = dim, coalesced bf16 v gathers; topk via scalar loads ----
  int off = 512 + h * 64 + lane;
  float acc = 0.f;
  #pragma unroll
  for (int j = 0; j < NN_K; ++j) {
    int ij = topk[n * NN_K + j];        // block-uniform -> s_load, L1-hot
    acc += pv[j] * bf2f_bits(kv[(size_t)ij * 1024 + off]);
  }
  ctx_bf[rb + h * 64 + lane] = (short)f2bf(acc);
}

// ---------------------------------------------------------------------------
extern "C" void kernel_launch(void* const* d_in, const int* in_sizes, int n_in,
                              void* d_out, int out_size, void* d_ws, size_t ws_size,
                              hipStream_t stream) {
  const float* x       = (const float*)d_in[0];
  const float* coords9 = (const float*)d_in[1];
  const float* prompt  = (const float*)d_in[2];
  const float* pos_w1  = (const float*)d_in[3];
  const float* pos_b1  = (const float*)d_in[4];
  const float* ln_g    = (const float*)d_in[5];
  const float* ln_b    = (const float*)d_in[6];
  const float* wq      = (const float*)d_in[7];
  const float* wk      = (const float*)d_in[8];
  const float* wv      = (const float*)d_in[9];
  const float* bq      = (const float*)d_in[10];
  const float* bk      = (const float*)d_in[11];
  const float* bv      = (const float*)d_in[12];
  const float* wo      = (const float*)d_in[13];
  const float* bo      = (const float*)d_in[14];

  int N = in_sizes[1] / 9;                       // 2000
  int Mpad = (N + 127) & ~127;                   // 2048
  size_t PE = (size_t)Mpad * E_DIM;

  char* p = (char*)d_ws;
  short* pos_bf = (short*)p; p += PE * 2;                      // 2 MB
  short* w_bf   = (short*)p; p += (size_t)4 * 512 * 512 * 2;   // 2 MB
  float* qb     = (float*)p; p += PE * 4;                      // 4 MB
  short* kv_bf  = (short*)p; p += PE * 2 * 2;                  // 4 MB (k|v bf16)
  short* ctx_bf = (short*)p; p += PE * 2;                      // 2 MB
  float* cent   = (float*)p; p += (size_t)N * 3 * 4;
  int*   topk   = (int*)p;                                     // N*32 ints

  wconv_kernel<<<1024, 256, 0, stream>>>(wq, wk, wv, wo, w_bf);
  pos_kernel<<<Mpad, 128, 0, stream>>>(x, coords9, prompt, pos_w1, pos_b1,
                                       ln_g, ln_b, pos_bf, cent, N);
  topk_kernel<<<N, 256, 0, stream>>>(cent, topk, N);

  dim3 gq(Mpad / 128, 12);
  qkv_mfma<<<gq, 256, 0, stream>>>(pos_bf, w_bf, bq, bk, bv, qb, kv_bf, Mpad);
  attn_kernel<<<Mpad, 512, 0, stream>>>(qb, kv_bf, topk, ctx_bf, N);

  dim3 go(Mpad / 128, 4);
  out_mfma<<<go, 256, 0, stream>>>(ctx_bf, w_bf, bo, (float*)d_out, N);
}

// Round 6
// 152.865 us; speedup vs baseline: 1.6796x; 1.0990x over previous
//
#include <hip/hip_runtime.h>
#include <math.h>

#define NN_K 32
#define E_DIM 512
#define CLAMP_V 10000.0f

typedef __attribute__((ext_vector_type(8))) short short8;
typedef __attribute__((ext_vector_type(4))) float f32x4;

// bf16 RTNE, bit-level
__device__ __forceinline__ unsigned short f2bf(float x) {
  unsigned u = __float_as_uint(x);
  unsigned r = u + 0x7fffu + ((u >> 16) & 1u);
  return (unsigned short)(r >> 16);
}
__device__ __forceinline__ float bf2f_bits(short h) {
  return __uint_as_float(((unsigned)(unsigned short)h) << 16);
}

__device__ __forceinline__ void async16(const void* g, void* l) {
  __builtin_amdgcn_global_load_lds((const __attribute__((address_space(1))) void*)g,
                                   (__attribute__((address_space(3))) void*)l, 16, 0, 0);
}

// ---------------------------------------------------------------------------
// Kernel 1 (fused front): grid-partitioned independent phases.
//   blocks [0,256):        wconv  — 4 weight matrices fp32 -> bf16
//   blocks [256,2304):     pos    — centroid+Linear(3,128)+GELU+LN+concat
//   blocks [2304,4304):    topk   — radix select over candidate centroids
//                                   (centroids recomputed from coords9 —
//                                   bit-identical to pos's, no dependency)
// ---------------------------------------------------------------------------
__global__ __launch_bounds__(256) void front_kernel(
    const float* __restrict__ x, const float* __restrict__ coords9,
    const float* __restrict__ prompt,
    const float* __restrict__ w1, const float* __restrict__ b1,
    const float* __restrict__ ln_g, const float* __restrict__ ln_b,
    const float* __restrict__ wq, const float* __restrict__ wk,
    const float* __restrict__ wv, const float* __restrict__ wo,
    short* __restrict__ w_bf, short* __restrict__ pos_bf,
    int* __restrict__ topk, int N, int Mpad)
{
  int blk = blockIdx.x;
  int t = threadIdx.x;

  if (blk < 256) {
    // ---- wconv: 262144 float4s over 256 blocks x 256 thr x 4 ----
    #pragma unroll
    for (int i = 0; i < 4; ++i) {
      int v = blk * 256 + t + i * 65536;
      int m = v >> 16;
      int e = v & 0xffff;
      const float* src = m == 0 ? wq : (m == 1 ? wk : (m == 2 ? wv : wo));
      float4 f = ((const float4*)src)[e];
      short4 h;
      h.x = (short)f2bf(f.x); h.y = (short)f2bf(f.y);
      h.z = (short)f2bf(f.z); h.w = (short)f2bf(f.w);
      ((short4*)w_bf)[v] = h;
    }
    return;
  }

  if (blk < 2304) {
    // ---- pos: one row per block; threads t<128 run the encoder ----
    int n = blk - 256;
    size_t rb = (size_t)n * E_DIM;
    if (n >= N) {
      #pragma unroll
      for (int j = t; j < E_DIM; j += 256) pos_bf[rb + j] = 0;
      return;
    }
    __shared__ float red[4];
    float g = 0.f;
    if (t < 128) {
      const float* c9 = coords9 + n * 9;
      float c0 = (c9[0] + c9[3] + c9[6]) / 3.0f;
      float c1 = (c9[1] + c9[4] + c9[7]) / 3.0f;
      float c2 = (c9[2] + c9[5] + c9[8]) / 3.0f;
      float pre = c0 * w1[t*3+0] + c1 * w1[t*3+1] + c2 * w1[t*3+2] + b1[t];
      g = 0.5f * pre * (1.0f + erff(pre * 0.70710678118654752440f));
      float s = g;
      #pragma unroll
      for (int o = 32; o > 0; o >>= 1) s += __shfl_xor(s, o);
      if ((t & 63) == 0) red[t >> 6] = s;
    }
    __syncthreads();
    float mu = (red[0] + red[1]) * (1.0f / 128.0f);
    float d = g - mu;
    if (t < 128) {
      float s2 = d * d;
      #pragma unroll
      for (int o = 32; o > 0; o >>= 1) s2 += __shfl_xor(s2, o);
      if ((t & 63) == 0) red[2 + (t >> 6)] = s2;
    }
    __syncthreads();
    if (t < 128) {
      float var = (red[2] + red[3]) * (1.0f / 128.0f);
      float y = d * rsqrtf(var + 1e-5f) * ln_g[t] + ln_b[t];
      pos_bf[rb + 384 + t] = (short)f2bf(y);
    }
    #pragma unroll
    for (int j = t; j < 384; j += 256)
      pos_bf[rb + j] = (short)f2bf(x[rb + j] + prompt[j]);
    return;
  }

  // ---- topk: 4-pass radix select; centroids computed inline ----
  {
    __shared__ unsigned hist[256];
    __shared__ unsigned waveSums[4];
    __shared__ unsigned sel_bin, sel_rem;
    __shared__ unsigned cnt, tcnt;
    __shared__ unsigned tie[2048];

    int n = blk - 2304;
    int lane = t & 63, wid = t >> 6;
    const float* cn = coords9 + n * 9;
    float cx = (cn[0] + cn[3] + cn[6]) / 3.0f;
    float cy = (cn[1] + cn[4] + cn[7]) / 3.0f;
    float cz = (cn[2] + cn[5] + cn[8]) / 3.0f;

    unsigned bits[8];
    #pragma unroll
    for (int r = 0; r < 8; ++r) {
      int m = t + (r << 8);
      unsigned b = 0xFFFFFFFFu;
      if (m < N) {
        const float* cm = coords9 + m * 9;
        float mx_ = (cm[0] + cm[3] + cm[6]) / 3.0f;
        float my_ = (cm[1] + cm[4] + cm[7]) / 3.0f;
        float mz_ = (cm[2] + cm[5] + cm[8]) / 3.0f;
        float dx = cx - mx_, dy = cy - my_, dz = cz - mz_;
        float dist = sqrtf(dx*dx + dy*dy + dz*dz);
        b = __float_as_uint(dist);
      }
      bits[r] = b;
    }

    unsigned prefix = 0;
    unsigned K_rem = NN_K;
    #pragma unroll
    for (int p = 0; p < 4; ++p) {
      int shift = 24 - 8 * p;
      unsigned high_mask = (p == 0) ? 0u : (0xFFFFFFFFu << (8 * (4 - p)));
      hist[t] = 0;
      __syncthreads();
      #pragma unroll
      for (int r = 0; r < 8; ++r) {
        if ((bits[r] & high_mask) == prefix)
          atomicAdd(&hist[(bits[r] >> shift) & 255], 1u);
      }
      __syncthreads();
      unsigned h = hist[t];
      unsigned scan = h;
      #pragma unroll
      for (int o = 1; o < 64; o <<= 1) {
        unsigned u = __shfl_up(scan, o);
        if (lane >= o) scan += u;
      }
      if (lane == 63) waveSums[wid] = scan;
      __syncthreads();
      unsigned off = 0;
      for (int w = 0; w < wid; ++w) off += waveSums[w];
      scan += off;
      if (scan >= K_rem && (scan - h) < K_rem) {
        sel_bin = (unsigned)t;
        sel_rem = K_rem - (scan - h);
      }
      __syncthreads();
      prefix |= sel_bin << shift;
      K_rem = sel_rem;
      __syncthreads();
    }

    unsigned T = prefix;
    if (t == 0) { cnt = 0; tcnt = 0; }
    __syncthreads();
    #pragma unroll
    for (int r = 0; r < 8; ++r) {
      int m = t + (r << 8);
      if (m < N) {
        if (bits[r] < T) {
          unsigned slot = atomicAdd(&cnt, 1u);
          topk[n * NN_K + slot] = m;
        } else if (bits[r] == T) {
          unsigned tp = atomicAdd(&tcnt, 1u);
          tie[tp] = (unsigned)m;
        }
      }
    }
    __syncthreads();
    if (t == 0) {
      unsigned base = cnt;
      unsigned need = K_rem;
      for (unsigned it = 0; it < need; ++it) {
        unsigned best = 0xFFFFFFFFu, bj = 0;
        for (unsigned j = 0; j < tcnt; ++j)
          if (tie[j] < best) { best = tie[j]; bj = j; }
        topk[n * NN_K + base + it] = (int)best;
        tie[bj] = 0xFFFFFFFFu;
      }
    }
  }
}

// ---------------------------------------------------------------------------
// bf16 MFMA GEMM, 64x128 tile, double-buffered vmcnt(3)+s_barrier pipeline.
// 256 thr = 4 waves; wave w computes 64 rows x 32 cols (acc 4x2).
// 24 KB LDS, ~80 VGPR -> multiple blocks/CU for cross-block latency hiding.
// ---------------------------------------------------------------------------
__device__ __forceinline__ void gemm_core(
    const short* __restrict__ A, const short* __restrict__ W,
    const float* __restrict__ bias,
    float* __restrict__ outf, short* __restrict__ outb,
    int out_ld, int out_c0,
    int M, int row0, int col0, bool doClamp)
{
  __shared__ short sA[2][64 * 32], sB[2][128 * 32];
  int tid = threadIdx.x;
  int cr = tid >> 2;
  int ck = (tid & 3) << 3;
  const short* gA = A + (size_t)(row0 + cr) * 512 + ck;
  const short* gB = W + (size_t)(col0 + cr) * 512 + ck;
  int lo = tid * 8, loB1 = (tid + 256) * 8;
  const size_t rstep = (size_t)64 * 512;

  int lane = tid & 63, wv_ = tid >> 6;
  int wn = wv_ << 5;                       // wave col offset 0/32/64/96
  int lr = lane & 15, lq = lane >> 4;

#define STAGE(t, b) do { \
    async16(gA + (t) * 32,         &sA[b][lo]); \
    async16(gB + (t) * 32,         &sB[b][lo]); \
    async16(gB + (t) * 32 + rstep, &sB[b][loB1]); } while (0)

  STAGE(0, 0);
  STAGE(1, 1);

  f32x4 acc[4][2];
  #pragma unroll
  for (int i = 0; i < 4; ++i)
    #pragma unroll
    for (int j = 0; j < 2; ++j)
      acc[i][j] = (f32x4){0.f, 0.f, 0.f, 0.f};

  #pragma unroll
  for (int it = 0; it < 16; ++it) {
    int cur = it & 1;
    if (it == 15) asm volatile("s_waitcnt vmcnt(0)\ns_barrier" ::: "memory");
    else          asm volatile("s_waitcnt vmcnt(3)\ns_barrier" ::: "memory");

    short8 af[4], bf[2];
    #pragma unroll
    for (int i = 0; i < 4; ++i)
      af[i] = *(const short8*)&sA[cur][((i << 4) + lr) * 32 + (lq << 3)];
    #pragma unroll
    for (int j = 0; j < 2; ++j)
      bf[j] = *(const short8*)&sB[cur][(wn + (j << 4) + lr) * 32 + (lq << 3)];
    #pragma unroll
    for (int i = 0; i < 4; ++i)
      #pragma unroll
      for (int j = 0; j < 2; ++j)
        acc[i][j] = __builtin_amdgcn_mfma_f32_16x16x32_bf16(af[i], bf[j], acc[i][j], 0, 0, 0);

    asm volatile("s_waitcnt lgkmcnt(0)\ns_barrier" ::: "memory");
    if (it + 2 < 16) STAGE(it + 2, cur);
  }
#undef STAGE

  #pragma unroll
  for (int j = 0; j < 2; ++j) {
    int gcol = col0 + wn + (j << 4) + lr;
    float bv_ = bias[gcol];
    #pragma unroll
    for (int i = 0; i < 4; ++i) {
      #pragma unroll
      for (int r = 0; r < 4; ++r) {
        int grow = row0 + (i << 4) + (lq << 2) + r;
        if (grow < M) {
          float v = acc[i][j][r] + bv_;
          if (doClamp) {
            v = isnan(v) ? 0.0f : v;
            v = fminf(fmaxf(v, -CLAMP_V), CLAMP_V);
          }
          if (outf) outf[(size_t)grow * 512 + gcol] = v;
          else      outb[(size_t)grow * out_ld + out_c0 + gcol] = (short)f2bf(v);
        }
      }
    }
  }
}

__global__ __launch_bounds__(256) void qkv_mfma(
    const short* __restrict__ A, const short* __restrict__ Wb,
    const float* __restrict__ bq, const float* __restrict__ bk, const float* __restrict__ bv,
    float* __restrict__ qb, short* __restrict__ kv, int M)
{
  int sel = blockIdx.y >> 2;
  int nblk = blockIdx.y & 3;
  int r0 = blockIdx.x * 64, c0 = nblk * 128;
  if (sel == 0)
    gemm_core(A, Wb, bq, qb, nullptr, 512, 0, M, r0, c0, false);
  else if (sel == 1)
    gemm_core(A, Wb + 262144, bk, nullptr, kv, 1024, 0, M, r0, c0, false);
  else
    gemm_core(A, Wb + 2 * 262144, bv, nullptr, kv, 1024, 512, M, r0, c0, false);
}

__global__ __launch_bounds__(256) void out_mfma(
    const short* __restrict__ A, const short* __restrict__ Wb,
    const float* __restrict__ bias, float* __restrict__ out, int M)
{
  gemm_core(A, Wb + (size_t)3 * 262144, bias, out, nullptr, 512, 0, M,
            blockIdx.x * 64, blockIdx.y * 128, true);
}

// ---------------------------------------------------------------------------
// Kernel 3: sparse top-K attention, lane-per-key scores, b64 LDS reads.
// ---------------------------------------------------------------------------
__global__ __launch_bounds__(512) void attn_kernel(
    const float* __restrict__ qb, const short* __restrict__ kv,
    const int* __restrict__ topk, short* __restrict__ ctx_bf, int N)
{
  __shared__ short klds[32 * 512];     // 32 KB, XOR-4 swizzled rows
  __shared__ int sidx[NN_K];
  __shared__ float plds[8 * 32];

  int n = blockIdx.x;
  int tid = threadIdx.x;
  size_t rb = (size_t)n * E_DIM;
  if (n >= N) { ctx_bf[rb + tid] = 0; return; }

  if (tid < NN_K) sidx[tid] = topk[n * NN_K + tid];
  __syncthreads();

  int h = tid >> 6, lane = tid & 63;
  int jk = lane & 31, half = lane >> 5;
  int dbase = h * 64 + half * 32;

  // ---- preload q head-slice to regs ----
  float qv[32];
  {
    const float4* qs = (const float4*)(qb + rb + dbase);
    #pragma unroll
    for (int b = 0; b < 8; ++b) {
      float4 f = qs[b];
      qv[b*4+0] = f.x; qv[b*4+1] = f.y; qv[b*4+2] = f.z; qv[b*4+3] = f.w;
    }
  }

  // ---- stage k rows (XOR-4 swizzle) ----
  {
    int j = tid >> 4, a = tid & 15;
    const short8* src = (const short8*)(kv + (size_t)sidx[j] * 1024 + a * 32);
    int sw = 4 * (j & 15);
    short* row = &klds[j * 512];
    #pragma unroll
    for (int b = 0; b < 4; ++b) {
      short8 val = src[b];
      int d0 = a * 32 + b * 8;
      *(short4*)&row[(d0    ) ^ sw] = *(const short4*)&val;
      *(short4*)&row[(d0 + 4) ^ sw] = *((const short4*)&val + 1);
    }
  }
  __syncthreads();

  // ---- scores: lane (jk,half) dot over its 32 dims, b64 LDS reads ----
  float s = 0.f;
  {
    int sw = 4 * (jk & 15);
    const short* krow = &klds[jk * 512];
    #pragma unroll
    for (int i4 = 0; i4 < 8; ++i4) {
      short4 kkv = *(const short4*)&krow[(dbase + i4 * 4) ^ sw];
      s += qv[i4*4+0] * bf2f_bits(kkv.x) + qv[i4*4+1] * bf2f_bits(kkv.y)
         + qv[i4*4+2] * bf2f_bits(kkv.z) + qv[i4*4+3] * bf2f_bits(kkv.w);
    }
  }
  s += __shfl_xor(s, 32);
  s *= 0.125f;

  // ---- softmax over 32 keys ----
  float mx = s;
  #pragma unroll
  for (int o = 16; o > 0; o >>= 1) mx = fmaxf(mx, __shfl_xor(mx, o));
  float p = expf(s - mx);
  float l = p;
  #pragma unroll
  for (int o = 16; o > 0; o >>= 1) l += __shfl_xor(l, o);
  p *= (1.0f / l);
  if (half == 0) plds[h * 32 + jk] = p;
  __syncthreads();

  float pv[32];
  #pragma unroll
  for (int b = 0; b < 8; ++b) {
    float4 f = *(const float4*)&plds[h * 32 + b * 4];
    pv[b*4+0] = f.x; pv[b*4+1] = f.y; pv[b*4+2] = f.z; pv[b*4+3] = f.w;
  }

  // ---- ctx: lane = dim, coalesced bf16 v gathers ----
  int off = 512 + h * 64 + lane;
  float acc = 0.f;
  #pragma unroll
  for (int j = 0; j < NN_K; ++j)
    acc += pv[j] * bf2f_bits(kv[(size_t)sidx[j] * 1024 + off]);
  ctx_bf[rb + h * 64 + lane] = (short)f2bf(acc);
}

// ---------------------------------------------------------------------------
extern "C" void kernel_launch(void* const* d_in, const int* in_sizes, int n_in,
                              void* d_out, int out_size, void* d_ws, size_t ws_size,
                              hipStream_t stream) {
  const float* x       = (const float*)d_in[0];
  const float* coords9 = (const float*)d_in[1];
  const float* prompt  = (const float*)d_in[2];
  const float* pos_w1  = (const float*)d_in[3];
  const float* pos_b1  = (const float*)d_in[4];
  const float* ln_g    = (const float*)d_in[5];
  const float* ln_b    = (const float*)d_in[6];
  const float* wq      = (const float*)d_in[7];
  const float* wk      = (const float*)d_in[8];
  const float* wv      = (const float*)d_in[9];
  const float* bq      = (const float*)d_in[10];
  const float* bk      = (const float*)d_in[11];
  const float* bv      = (const float*)d_in[12];
  const float* wo      = (const float*)d_in[13];
  const float* bo      = (const float*)d_in[14];

  int N = in_sizes[1] / 9;                       // 2000
  int Mpad = (N + 127) & ~127;                   // 2048
  size_t PE = (size_t)Mpad * E_DIM;

  char* p = (char*)d_ws;
  short* pos_bf = (short*)p; p += PE * 2;                      // 2 MB
  short* w_bf   = (short*)p; p += (size_t)4 * 512 * 512 * 2;   // 2 MB
  float* qb     = (float*)p; p += PE * 4;                      // 4 MB
  short* kv_bf  = (short*)p; p += PE * 2 * 2;                  // 4 MB (k|v)
  short* ctx_bf = (short*)p; p += PE * 2;                      // 2 MB
  int*   topk   = (int*)p;                                     // N*32 ints

  front_kernel<<<256 + Mpad + N, 256, 0, stream>>>(
      x, coords9, prompt, pos_w1, pos_b1, ln_g, ln_b,
      wq, wk, wv, wo, w_bf, pos_bf, topk, N, Mpad);

  dim3 gq(Mpad / 64, 12);
  qkv_mfma<<<gq, 256, 0, stream>>>(pos_bf, w_bf, bq, bk, bv, qb, kv_bf, Mpad);
  attn_kernel<<<Mpad, 512, 0, stream>>>(qb, kv_bf, topk, ctx_bf, N);

  dim3 go(Mpad / 64, 4);
  out_mfma<<<go, 256, 0, stream>>>(ctx_bf, w_bf, bo, (float*)d_out, N);
}